// Round 12
// baseline (382.922 us; speedup 1.0000x reference)
//
#include <hip/hip_runtime.h>
#include <hip/hip_bf16.h>

typedef _Float16 half8 __attribute__((ext_vector_type(8)));
typedef _Float16 half4 __attribute__((ext_vector_type(4)));
typedef short short8 __attribute__((ext_vector_type(8)));
typedef short short4v __attribute__((ext_vector_type(4)));
typedef float f32x4 __attribute__((ext_vector_type(4)));

#define BATCH 16
#define SEQ   4096
#define DIM   64
#define MTILE 64              // q rows per workgroup (4 waves x 16)
#define KVB   64              // key chunk
#define NCH   (SEQ / KVB)     // 64 chunks
#define NSC   (NCH / 2)       // 32 superchunks (128 keys) for pass 1
#define EL_CH 4096            // elems per chunk per tensor (512 frags * 8)
#define EL_B  (NCH * EL_CH)   // elems per batch per tensor (262144)

__device__ __forceinline__ short f2bf(float f) {
    unsigned u = __builtin_bit_cast(unsigned, f);
    u += 0x7FFF + ((u >> 16) & 1);          // round-to-nearest-even
    return (short)(u >> 16);
}
__device__ __forceinline__ float bf2f(short h) {
    return __builtin_bit_cast(float, (unsigned)((unsigned short)h) << 16);
}

__device__ __forceinline__ void gld16(const void* g, void* l) {
    __builtin_amdgcn_global_load_lds(
        (const __attribute__((address_space(1))) unsigned int*)g,
        (__attribute__((address_space(3))) unsigned int*)l, 16, 0, 0);
}

// ======== pre-kernel: K,V -> fp16 frag-linear (unchanged) ========
// K frag(ch,nf,kk,lane) = K[ch*64 + nf*16 + (lane&15)][kk*32 + (lane>>4)*8 + e]
// V frag(ch,nf,kk,lane) = V[ch*64 + kk*32 + (lane>>4)*8 + e][nf*16 + (lane&15)]
__global__ __launch_bounds__(256) void preconvert(
    const float* __restrict__ k, const float* __restrict__ v,
    _Float16* __restrict__ kh, _Float16* __restrict__ vh)
{
    int f = blockIdx.x * 256 + threadIdx.x;   // 0 .. 2*524288-1
    int lane = f & 63;
    int sub  = (f >> 6) & 7;                  // nf*2 + kk
    int ch   = (f >> 9) & 63;
    int bb   = (f >> 15) & 15;
    int isV  = f >> 19;
    int nf = sub >> 1, kk = sub & 1;
    size_t fo = (size_t)(f & ((1 << 19) - 1)) * 8;

    if (!isV) {
        int key = ch * 64 + nf * 16 + (lane & 15);
        int d0  = kk * 32 + (lane >> 4) * 8;
        const float* src = k + (((size_t)bb * SEQ + key) * DIM + d0);
        half8 h8;
        #pragma unroll
        for (int e = 0; e < 8; ++e) h8[e] = (_Float16)src[e];
        *(half8*)(kh + fo) = h8;
    } else {
        int kr0 = kk * 32 + (lane >> 4) * 8;
        int d   = nf * 16 + (lane & 15);
        const float* src = v + (((size_t)bb * SEQ + ch * 64 + kr0) * DIM + d);
        half8 h8;
        #pragma unroll
        for (int e = 0; e < 8; ++e) h8[e] = (_Float16)src[e * DIM];
        *(half8*)(vh + fo) = h8;
    }
}

// ============================== main kernel ==============================
// Swapped QK^T: s = mfma(A=K_frag, B=Q_frag) -> each thread owns ONE q-row
// (q = li) with keys {16nf + 4h4 + r}. Att stores go straight from registers
// as 64B-aligned 64B runs (4 h4-lanes x 16B). Pass 1 runs on 128-key
// superchunks using the K/V LDS pool aliased as 2 x 16KB buffers.
__global__ __launch_bounds__(256) void attn_main(
    const float* __restrict__ q, const _Float16* __restrict__ kh,
    const _Float16* __restrict__ vh, float* __restrict__ ctx,
    float* __restrict__ att)
{
    __shared__ _Float16 KV[2][8192];      // 32 KB pool
                                          // pass1: KV[b] = 128-key K superchunk b
                                          // pass2: KV[0][b*4096]=K buf b, KV[1][b*4096]=V buf b
    __shared__ _Float16 Ph[4][16][72];    // per-wave P fp16 [q][key] (9 KB)

    int id = blockIdx.x;                  // grid = 1024
    int bb = (id & 7) + 8 * (id >> 9);    // XCD-swizzled batch
    int qt = (id >> 3) & 63;

    int tid = threadIdx.x;
    int w = tid >> 6, lane = tid & 63, li = lane & 15, h4 = lane >> 4;

    // ---- Q B-fragments (fp16): this thread's q-row is qrow (q = li) ----
    int qrow = qt * MTILE + w * 16 + li;
    const float* qp = q + ((size_t)bb * SEQ + qrow) * DIM;
    half8 aq[2];
    #pragma unroll
    for (int kk = 0; kk < 2; ++kk)
        #pragma unroll
        for (int e = 0; e < 8; ++e)
            aq[kk][e] = (_Float16)qp[kk * 32 + h4 * 8 + e];

    const _Float16* khb = kh + (size_t)bb * EL_B;
    const _Float16* vvb = vh + (size_t)bb * EL_B;

    // swapped QK^T from a frag-linear LDS base: s[nf][r]=S[q=li][16nf+4h4+r]
    auto qkt = [&](const _Float16* base, f32x4* s) {
        const half8* k8 = (const half8*)base;
        #pragma unroll
        for (int kk = 0; kk < 2; ++kk)
            #pragma unroll
            for (int nf = 0; nf < 4; ++nf)
                s[nf] = __builtin_amdgcn_mfma_f32_16x16x32_f16(
                    k8[(nf * 2 + kk) * 64 + lane], aq[kk], s[nf], 0, 0, 0);
    };

    // ========== pass 1: l = sum exp(s), 128-key superchunks ==========
    float ll = 0.f;

    auto stage_sc = [&](int buf, int sc) {        // 16 KB superchunk
        const _Float16* g = khb + (size_t)sc * (2 * EL_CH) + tid * 8;
        gld16(g,        &KV[buf][w * 512]);
        gld16(g + 2048, &KV[buf][2048 + w * 512]);
        gld16(g + 4096, &KV[buf][4096 + w * 512]);
        gld16(g + 6144, &KV[buf][6144 + w * 512]);
    };

    stage_sc(0, 0);
    for (int sc = 0; sc < NSC; ++sc) {
        int buf = sc & 1;
        if (sc + 1 < NSC) {
            stage_sc(buf ^ 1, sc + 1);
            asm volatile("s_waitcnt vmcnt(4)" ::: "memory");
        } else {
            asm volatile("s_waitcnt vmcnt(0)" ::: "memory");
        }
        __builtin_amdgcn_s_barrier();
        asm volatile("" ::: "memory");

        #pragma unroll
        for (int c2 = 0; c2 < 2; ++c2) {
            f32x4 s[4];
            #pragma unroll
            for (int nf = 0; nf < 4; ++nf) s[nf] = (f32x4){0.f, 0.f, 0.f, 0.f};
            qkt(&KV[buf][c2 * EL_CH], s);
            float a = 0.f;
            #pragma unroll
            for (int nf = 0; nf < 4; ++nf)
                #pragma unroll
                for (int r = 0; r < 4; ++r)
                    a += __expf(s[nf][r]);
            ll += a;
        }

        asm volatile("" ::: "memory");
        __builtin_amdgcn_s_barrier();
    }

    // reduce over the 4 lanes sharing this q-row (h4 group), invert
    ll += __shfl_xor(ll, 16);
    ll += __shfl_xor(ll, 32);
    float rl = 1.0f / ll;

    // ========== pass 2: p = exp(s)*rl; direct reg->att stores; PV fp16 =====
    f32x4 acc[4];
    #pragma unroll
    for (int nf = 0; nf < 4; ++nf) acc[nf] = (f32x4){0.f, 0.f, 0.f, 0.f};

    // this thread's attention row (q = li)
    float* attr = att + ((size_t)bb * SEQ + (size_t)qt * MTILE + w * 16 + li) * SEQ;

    auto stage_k = [&](int buf, int ch) {
        const _Float16* g = khb + (size_t)ch * EL_CH + tid * 8;
        gld16(g,        &KV[0][buf * EL_CH + w * 512]);
        gld16(g + 2048, &KV[0][buf * EL_CH + 2048 + w * 512]);
    };
    auto stage_v = [&](int buf, int ch) {
        const _Float16* g = vvb + (size_t)ch * EL_CH + tid * 8;
        gld16(g,        &KV[1][buf * EL_CH + w * 512]);
        gld16(g + 2048, &KV[1][buf * EL_CH + 2048 + w * 512]);
    };

    stage_k(0, 0); stage_v(0, 0);
    for (int ch = 0; ch < NCH; ++ch) {
        int buf = ch & 1;
        if (ch + 1 < NCH) {
            stage_k(buf ^ 1, ch + 1);
            stage_v(buf ^ 1, ch + 1);
            // queue: [4 loads cur][4 stores prev][4 loads next]
            if (ch == 0) asm volatile("s_waitcnt vmcnt(4)" ::: "memory");
            else         asm volatile("s_waitcnt vmcnt(8)" ::: "memory");
        } else {
            asm volatile("s_waitcnt vmcnt(4)" ::: "memory");
        }
        __builtin_amdgcn_s_barrier();
        asm volatile("" ::: "memory");

        f32x4 s[4];
        #pragma unroll
        for (int nf = 0; nf < 4; ++nf) s[nf] = (f32x4){0.f, 0.f, 0.f, 0.f};
        qkt(&KV[0][buf * EL_CH], s);

        // p = exp(s)*rl: Ph write (for PV) + DIRECT att store (64B runs)
        #pragma unroll
        for (int nf = 0; nf < 4; ++nf) {
            half4 p4;
            f32x4 pv;
            #pragma unroll
            for (int r = 0; r < 4; ++r) {
                float p = __expf(s[nf][r]) * rl;
                p4[r] = (_Float16)p;
                pv[r] = p;
            }
            *(half4*)&Ph[w][li][nf * 16 + h4 * 4] = p4;
            __builtin_nontemporal_store(
                pv, (f32x4*)(attr + ch * KVB + nf * 16 + h4 * 4));
        }

        // PV (fp16): acc[q][d] += P[q][key] * V[key][d]
        const half8* v8 = (const half8*)&KV[1][buf * EL_CH];
        #pragma unroll
        for (int kk = 0; kk < 2; ++kk) {
            half8 pa = *(const half8*)&Ph[w][li][kk * 32 + h4 * 8];
            #pragma unroll
            for (int nf = 0; nf < 4; ++nf)
                acc[nf] = __builtin_amdgcn_mfma_f32_16x16x32_f16(
                    pa, v8[(nf * 2 + kk) * 64 + lane], acc[nf], 0, 0, 0);
        }

        asm volatile("" ::: "memory");
        __builtin_amdgcn_s_barrier();
    }

    float* ctxb = ctx + ((size_t)bb * SEQ + (size_t)qt * MTILE + w * 16) * DIM;
    #pragma unroll
    for (int nf = 0; nf < 4; ++nf)
        #pragma unroll
        for (int r = 0; r < 4; ++r)
            __builtin_nontemporal_store(
                acc[nf][r], &ctxb[(size_t)(4 * h4 + r) * DIM + nf * 16 + li]);
}

// ===================== fallback (round-2 kernel, proven) =====================
__global__ __launch_bounds__(256) void attn_fallback(
    const float* __restrict__ q, const float* __restrict__ k,
    const float* __restrict__ v, float* __restrict__ ctx,
    float* __restrict__ att)
{
    __shared__ short K_hi[KVB][72];
    __shared__ short K_lo[KVB][72];
    __shared__ short V_lds[DIM][72];
    __shared__ short P_lds[4][16][72];

    int id = blockIdx.x;
    int bb = (id & 7) + 8 * (id >> 9);
    int qt = (id >> 3) & 63;
    int tid = threadIdx.x;
    int w = tid >> 6, lane = tid & 63, li = lane & 15, h4 = lane >> 4;

    int qrow = qt * 64 + w * 16 + li;
    const float* qp = q + ((size_t)bb * SEQ + qrow) * DIM;
    short8 aq[2], aql[2];
    #pragma unroll
    for (int kk = 0; kk < 2; ++kk)
        #pragma unroll
        for (int e = 0; e < 8; ++e) {
            float x = qp[kk * 32 + h4 * 8 + e];
            short h = f2bf(x);
            aq[kk][e] = h; aql[kk][e] = f2bf(x - bf2f(h));
        }

    float m[4], l[4];
    #pragma unroll
    for (int r = 0; r < 4; ++r) { m[r] = -3.0e38f; l[r] = 0.0f; }
    const float* kbase = k + (size_t)bb * SEQ * DIM;
    const float* vbase = v + (size_t)bb * SEQ * DIM;

    for (int ch = 0; ch < NCH; ++ch) {
        __syncthreads();
        const float4* kc = (const float4*)(kbase + (size_t)ch * KVB * DIM);
        #pragma unroll
        for (int j = 0; j < 4; ++j) {
            int f4 = j * 256 + tid; int key = f4 >> 4, d4 = f4 & 15;
            float4 val = kc[f4];
            short4v h4v, l4v;
            h4v[0]=f2bf(val.x); l4v[0]=f2bf(val.x-bf2f(h4v[0]));
            h4v[1]=f2bf(val.y); l4v[1]=f2bf(val.y-bf2f(h4v[1]));
            h4v[2]=f2bf(val.z); l4v[2]=f2bf(val.z-bf2f(h4v[2]));
            h4v[3]=f2bf(val.w); l4v[3]=f2bf(val.w-bf2f(h4v[3]));
            *(short4v*)&K_hi[key][d4*4] = h4v;
            *(short4v*)&K_lo[key][d4*4] = l4v;
        }
        __syncthreads();
        f32x4 s[4];
        #pragma unroll
        for (int nf = 0; nf < 4; ++nf) s[nf] = (f32x4){0.f,0.f,0.f,0.f};
        #pragma unroll
        for (int kk = 0; kk < 2; ++kk)
            #pragma unroll
            for (int nf = 0; nf < 4; ++nf) {
                short8 kbv = *(const short8*)&K_hi[nf*16+li][kk*32+h4*8];
                short8 klv = *(const short8*)&K_lo[nf*16+li][kk*32+h4*8];
                s[nf] = __builtin_amdgcn_mfma_f32_16x16x32_bf16(aq[kk],  kbv, s[nf],0,0,0);
                s[nf] = __builtin_amdgcn_mfma_f32_16x16x32_bf16(aq[kk],  klv, s[nf],0,0,0);
                s[nf] = __builtin_amdgcn_mfma_f32_16x16x32_bf16(aql[kk], kbv, s[nf],0,0,0);
            }
        #pragma unroll
        for (int r = 0; r < 4; ++r) {
            float cmax = fmaxf(fmaxf(s[0][r],s[1][r]), fmaxf(s[2][r],s[3][r]));
            #pragma unroll
            for (int off = 1; off < 16; off <<= 1) cmax = fmaxf(cmax, __shfl_xor(cmax, off));
            float mnew = fmaxf(m[r], cmax);
            float cs = __expf(s[0][r]-mnew)+__expf(s[1][r]-mnew)+__expf(s[2][r]-mnew)+__expf(s[3][r]-mnew);
            #pragma unroll
            for (int off = 1; off < 16; off <<= 1) cs += __shfl_xor(cs, off);
            l[r] = l[r]*__expf(m[r]-mnew) + cs; m[r] = mnew;
        }
    }
    float rl[4];
    #pragma unroll
    for (int r = 0; r < 4; ++r) rl[r] = 1.0f / l[r];

    f32x4 acc[4];
    #pragma unroll
    for (int nf = 0; nf < 4; ++nf) acc[nf] = (f32x4){0.f,0.f,0.f,0.f};
    float* attb = att + ((size_t)bb * SEQ + (size_t)qt * 64 + w * 16) * SEQ;

    for (int ch = 0; ch < NCH; ++ch) {
        __syncthreads();
        const float4* kc = (const float4*)(kbase + (size_t)ch * KVB * DIM);
        #pragma unroll
        for (int j = 0; j < 4; ++j) {
            int f4 = j * 256 + tid; int key = f4 >> 4, d4 = f4 & 15;
            float4 val = kc[f4];
            short4v h4v, l4v;
            h4v[0]=f2bf(val.x); l4v[0]=f2bf(val.x-bf2f(h4v[0]));
            h4v[1]=f2bf(val.y); l4v[1]=f2bf(val.y-bf2f(h4v[1]));
            h4v[2]=f2bf(val.z); l4v[2]=f2bf(val.z-bf2f(h4v[2]));
            h4v[3]=f2bf(val.w); l4v[3]=f2bf(val.w-bf2f(h4v[3]));
            *(short4v*)&K_hi[key][d4*4] = h4v;
            *(short4v*)&K_lo[key][d4*4] = l4v;
        }
        {
            int key = tid & 63, dblk = (tid >> 6) * 16;
            const float* vc = vbase + ((size_t)ch * KVB + key) * DIM + dblk;
            #pragma unroll
            for (int j = 0; j < 4; ++j) {
                float4 val = *(const float4*)(vc + j * 4);
                V_lds[dblk+j*4+0][key]=f2bf(val.x); V_lds[dblk+j*4+1][key]=f2bf(val.y);
                V_lds[dblk+j*4+2][key]=f2bf(val.z); V_lds[dblk+j*4+3][key]=f2bf(val.w);
            }
        }
        __syncthreads();
        f32x4 s[4];
        #pragma unroll
        for (int nf = 0; nf < 4; ++nf) s[nf] = (f32x4){0.f,0.f,0.f,0.f};
        #pragma unroll
        for (int kk = 0; kk < 2; ++kk)
            #pragma unroll
            for (int nf = 0; nf < 4; ++nf) {
                short8 kbv = *(const short8*)&K_hi[nf*16+li][kk*32+h4*8];
                short8 klv = *(const short8*)&K_lo[nf*16+li][kk*32+h4*8];
                s[nf] = __builtin_amdgcn_mfma_f32_16x16x32_bf16(aq[kk],  kbv, s[nf],0,0,0);
                s[nf] = __builtin_amdgcn_mfma_f32_16x16x32_bf16(aq[kk],  klv, s[nf],0,0,0);
                s[nf] = __builtin_amdgcn_mfma_f32_16x16x32_bf16(aql[kk], kbv, s[nf],0,0,0);
            }
        #pragma unroll
        for (int nf = 0; nf < 4; ++nf)
            #pragma unroll
            for (int r = 0; r < 4; ++r) {
                float p = __expf(s[nf][r] - m[r]) * rl[r];
                __builtin_nontemporal_store(p, &attb[(size_t)(4*h4+r)*SEQ + ch*KVB + nf*16 + li]);
                P_lds[w][4*h4+r][nf*16+li] = f2bf(p);
            }
        #pragma unroll
        for (int kk = 0; kk < 2; ++kk) {
            short8 pa = *(const short8*)&P_lds[w][li][kk*32+h4*8];
            #pragma unroll
            for (int nf = 0; nf < 4; ++nf) {
                short8 vbv = *(const short8*)&V_lds[nf*16+li][kk*32+h4*8];
                acc[nf] = __builtin_amdgcn_mfma_f32_16x16x32_bf16(pa, vbv, acc[nf],0,0,0);
            }
        }
    }
    float* ctxb = ctx + ((size_t)bb * SEQ + (size_t)qt * 64 + w * 16) * DIM;
    #pragma unroll
    for (int nf = 0; nf < 4; ++nf)
        #pragma unroll
        for (int r = 0; r < 4; ++r)
            __builtin_nontemporal_store(acc[nf][r], &ctxb[(size_t)(4*h4+r)*DIM + nf*16 + li]);
}

extern "C" void kernel_launch(void* const* d_in, const int* in_sizes, int n_in,
                              void* d_out, int out_size, void* d_ws, size_t ws_size,
                              hipStream_t stream) {
    const float* q = (const float*)d_in[0];
    const float* k = (const float*)d_in[1];
    const float* v = (const float*)d_in[2];
    float* ctx = (float*)d_out;
    float* att = (float*)d_out + (size_t)BATCH * SEQ * DIM;

    const size_t t_el = (size_t)BATCH * EL_B;              // 4,194,304
    const size_t need = 2 * t_el * 2;                      // 16.8 MB

    if (ws_size >= need) {
        _Float16* kh = (_Float16*)d_ws;
        _Float16* vh = kh + t_el;
        preconvert<<<4096, 256, 0, stream>>>(k, v, kh, vh);
        attn_main<<<BATCH * (SEQ / MTILE), 256, 0, stream>>>(q, kh, vh, ctx, att);
    } else {
        attn_fallback<<<BATCH * (SEQ / 64), 256, 0, stream>>>(q, k, v, ctx, att);
    }
}

// Round 13
// 292.929 us; speedup vs baseline: 1.3072x; 1.3072x over previous
//
#include <hip/hip_runtime.h>
#include <hip/hip_bf16.h>

typedef _Float16 half8 __attribute__((ext_vector_type(8)));
typedef _Float16 half4 __attribute__((ext_vector_type(4)));
typedef short short8 __attribute__((ext_vector_type(8)));
typedef short short4v __attribute__((ext_vector_type(4)));
typedef float f32x4 __attribute__((ext_vector_type(4)));

#define BATCH 16
#define SEQ   4096
#define DIM   64
#define MTILE 64              // q rows per workgroup (4 waves x 16)
#define KVB   64              // key chunk
#define NCH   (SEQ / KVB)     // 64 chunks
#define NSC   (NCH / 2)       // 32 superchunks (128 keys) for pass 1
#define EL_CH 4096            // elems per chunk per tensor (512 frags * 8)
#define EL_B  (NCH * EL_CH)   // elems per batch per tensor (262144)

__device__ __forceinline__ short f2bf(float f) {
    unsigned u = __builtin_bit_cast(unsigned, f);
    u += 0x7FFF + ((u >> 16) & 1);          // round-to-nearest-even
    return (short)(u >> 16);
}
__device__ __forceinline__ float bf2f(short h) {
    return __builtin_bit_cast(float, (unsigned)((unsigned short)h) << 16);
}

__device__ __forceinline__ void gld16(const void* g, void* l) {
    __builtin_amdgcn_global_load_lds(
        (const __attribute__((address_space(1))) unsigned int*)g,
        (__attribute__((address_space(3))) unsigned int*)l, 16, 0, 0);
}

// ======== pre-kernel: K,V -> fp16 frag-linear (unchanged) ========
// K frag(ch,nf,kk,lane) = K[ch*64 + nf*16 + (lane&15)][kk*32 + (lane>>4)*8 + e]
// V frag(ch,nf,kk,lane) = V[ch*64 + kk*32 + (lane>>4)*8 + e][nf*16 + (lane&15)]
__global__ __launch_bounds__(256) void preconvert(
    const float* __restrict__ k, const float* __restrict__ v,
    _Float16* __restrict__ kh, _Float16* __restrict__ vh)
{
    int f = blockIdx.x * 256 + threadIdx.x;   // 0 .. 2*524288-1
    int lane = f & 63;
    int sub  = (f >> 6) & 7;                  // nf*2 + kk
    int ch   = (f >> 9) & 63;
    int bb   = (f >> 15) & 15;
    int isV  = f >> 19;
    int nf = sub >> 1, kk = sub & 1;
    size_t fo = (size_t)(f & ((1 << 19) - 1)) * 8;

    if (!isV) {
        int key = ch * 64 + nf * 16 + (lane & 15);
        int d0  = kk * 32 + (lane >> 4) * 8;
        const float* src = k + (((size_t)bb * SEQ + key) * DIM + d0);
        half8 h8;
        #pragma unroll
        for (int e = 0; e < 8; ++e) h8[e] = (_Float16)src[e];
        *(half8*)(kh + fo) = h8;
    } else {
        int kr0 = kk * 32 + (lane >> 4) * 8;
        int d   = nf * 16 + (lane & 15);
        const float* src = v + (((size_t)bb * SEQ + ch * 64 + kr0) * DIM + d);
        half8 h8;
        #pragma unroll
        for (int e = 0; e < 8; ++e) h8[e] = (_Float16)src[e * DIM];
        *(half8*)(vh + fo) = h8;
    }
}

// ============================== main kernel ==============================
// r11 skeleton (swapped QK^T, Ph-based 256B att stores, fp16 PV) with
// pass 1 on 128-key superchunks via the aliased K/V LDS pool.
__global__ __launch_bounds__(256) void attn_main(
    const float* __restrict__ q, const _Float16* __restrict__ kh,
    const _Float16* __restrict__ vh, float* __restrict__ ctx,
    float* __restrict__ att)
{
    __shared__ _Float16 KV[2][8192];      // 32 KB pool
                                          // pass1: KV[b] = 128-key K superchunk b
                                          // pass2: KV[0] = K dbuf, KV[1] = V dbuf
    __shared__ _Float16 Ph[4][16][72];    // per-wave P fp16 [q][key] (9 KB)

    int id = blockIdx.x;                  // grid = 1024
    int bb = (id & 7) + 8 * (id >> 9);    // XCD-swizzled batch
    int qt = (id >> 3) & 63;

    int tid = threadIdx.x;
    int w = tid >> 6, lane = tid & 63, li = lane & 15, h4 = lane >> 4;

    // ---- Q B-fragments (fp16): this thread's q-row is qrow (q = li) ----
    int qrow = qt * MTILE + w * 16 + li;
    const float* qp = q + ((size_t)bb * SEQ + qrow) * DIM;
    half8 aq[2];
    #pragma unroll
    for (int kk = 0; kk < 2; ++kk)
        #pragma unroll
        for (int e = 0; e < 8; ++e)
            aq[kk][e] = (_Float16)qp[kk * 32 + h4 * 8 + e];

    const _Float16* khb = kh + (size_t)bb * EL_B;
    const _Float16* vvb = vh + (size_t)bb * EL_B;

    // swapped QK^T from a frag-linear LDS base: s[nf][r]=S[q=li][16nf+4h4+r]
    auto qkt = [&](const _Float16* base, f32x4* s) {
        const half8* k8 = (const half8*)base;
        #pragma unroll
        for (int kk = 0; kk < 2; ++kk)
            #pragma unroll
            for (int nf = 0; nf < 4; ++nf)
                s[nf] = __builtin_amdgcn_mfma_f32_16x16x32_f16(
                    k8[(nf * 2 + kk) * 64 + lane], aq[kk], s[nf], 0, 0, 0);
    };

    // ========== pass 1: l = sum exp(s), 128-key superchunks ==========
    float ll = 0.f;

    auto stage_sc = [&](int buf, int sc) {        // 16 KB superchunk
        const _Float16* g = khb + (size_t)sc * (2 * EL_CH) + tid * 8;
        gld16(g,        &KV[buf][w * 512]);
        gld16(g + 2048, &KV[buf][2048 + w * 512]);
        gld16(g + 4096, &KV[buf][4096 + w * 512]);
        gld16(g + 6144, &KV[buf][6144 + w * 512]);
    };

    stage_sc(0, 0);
    for (int sc = 0; sc < NSC; ++sc) {
        int buf = sc & 1;
        if (sc + 1 < NSC) {
            stage_sc(buf ^ 1, sc + 1);
            asm volatile("s_waitcnt vmcnt(4)" ::: "memory");
        } else {
            asm volatile("s_waitcnt vmcnt(0)" ::: "memory");
        }
        __builtin_amdgcn_s_barrier();
        asm volatile("" ::: "memory");

        #pragma unroll
        for (int c2 = 0; c2 < 2; ++c2) {
            f32x4 s[4];
            #pragma unroll
            for (int nf = 0; nf < 4; ++nf) s[nf] = (f32x4){0.f, 0.f, 0.f, 0.f};
            qkt(&KV[buf][c2 * EL_CH], s);
            float a = 0.f;
            #pragma unroll
            for (int nf = 0; nf < 4; ++nf)
                #pragma unroll
                for (int r = 0; r < 4; ++r)
                    a += __expf(s[nf][r]);
            ll += a;
        }

        asm volatile("" ::: "memory");
        __builtin_amdgcn_s_barrier();
    }

    // reduce over the 4 lanes sharing this q-row (h4 group), invert
    ll += __shfl_xor(ll, 16);
    ll += __shfl_xor(ll, 32);
    float rl = 1.0f / ll;

    // ========== pass 2: identical to r11 (proven 304.9 us) =================
    f32x4 acc[4];
    #pragma unroll
    for (int nf = 0; nf < 4; ++nf) acc[nf] = (f32x4){0.f, 0.f, 0.f, 0.f};

    float* attb = att + ((size_t)bb * SEQ + (size_t)qt * MTILE + w * 16) * SEQ;

    auto stage_k = [&](int buf, int ch) {
        const _Float16* g = khb + (size_t)ch * EL_CH + tid * 8;
        gld16(g,        &KV[0][buf * EL_CH + w * 512]);
        gld16(g + 2048, &KV[0][buf * EL_CH + 2048 + w * 512]);
    };
    auto stage_v = [&](int buf, int ch) {
        const _Float16* g = vvb + (size_t)ch * EL_CH + tid * 8;
        gld16(g,        &KV[1][buf * EL_CH + w * 512]);
        gld16(g + 2048, &KV[1][buf * EL_CH + 2048 + w * 512]);
    };

    stage_k(0, 0); stage_v(0, 0);
    for (int ch = 0; ch < NCH; ++ch) {
        int buf = ch & 1;
        if (ch + 1 < NCH) {
            stage_k(buf ^ 1, ch + 1);
            stage_v(buf ^ 1, ch + 1);
            // queue: [4 loads cur][4 stores prev][4 loads next]
            if (ch == 0) asm volatile("s_waitcnt vmcnt(4)" ::: "memory");
            else         asm volatile("s_waitcnt vmcnt(8)" ::: "memory");
        } else {
            asm volatile("s_waitcnt vmcnt(4)" ::: "memory");
        }
        __builtin_amdgcn_s_barrier();
        asm volatile("" ::: "memory");

        f32x4 s[4];
        #pragma unroll
        for (int nf = 0; nf < 4; ++nf) s[nf] = (f32x4){0.f, 0.f, 0.f, 0.f};
        qkt(&KV[0][buf * EL_CH], s);

        // p -> Ph[q=li][key]: 4 consecutive keys per write -> ds_write_b64
        #pragma unroll
        for (int nf = 0; nf < 4; ++nf) {
            half4 p4;
            #pragma unroll
            for (int r = 0; r < 4; ++r)
                p4[r] = (_Float16)(__expf(s[nf][r]) * rl);
            *(half4*)&Ph[w][li][nf * 16 + h4 * 4] = p4;
        }

        // att stores, 16-lane contiguous: 256B runs (proven; >=128B rule)
        #pragma unroll
        for (int j = 0; j < 4; ++j) {
            int row = j * 4 + h4;
            half4 ph = *(const half4*)&Ph[w][row][li * 4];
            f32x4 pv = { (float)ph[0], (float)ph[1], (float)ph[2], (float)ph[3] };
            __builtin_nontemporal_store(
                pv, (f32x4*)(attb + (size_t)row * SEQ + ch * KVB + li * 4));
        }

        // PV (fp16): acc[q][d] += P[q][key] * V[key][d]
        const half8* v8 = (const half8*)&KV[1][buf * EL_CH];
        #pragma unroll
        for (int kk = 0; kk < 2; ++kk) {
            half8 pa = *(const half8*)&Ph[w][li][kk * 32 + h4 * 8];
            #pragma unroll
            for (int nf = 0; nf < 4; ++nf)
                acc[nf] = __builtin_amdgcn_mfma_f32_16x16x32_f16(
                    pa, v8[(nf * 2 + kk) * 64 + lane], acc[nf], 0, 0, 0);
        }

        asm volatile("" ::: "memory");
        __builtin_amdgcn_s_barrier();
    }

    float* ctxb = ctx + ((size_t)bb * SEQ + (size_t)qt * MTILE + w * 16) * DIM;
    #pragma unroll
    for (int nf = 0; nf < 4; ++nf)
        #pragma unroll
        for (int r = 0; r < 4; ++r)
            __builtin_nontemporal_store(
                acc[nf][r], &ctxb[(size_t)(4 * h4 + r) * DIM + nf * 16 + li]);
}

// ===================== fallback (round-2 kernel, proven) =====================
__global__ __launch_bounds__(256) void attn_fallback(
    const float* __restrict__ q, const float* __restrict__ k,
    const float* __restrict__ v, float* __restrict__ ctx,
    float* __restrict__ att)
{
    __shared__ short K_hi[KVB][72];
    __shared__ short K_lo[KVB][72];
    __shared__ short V_lds[DIM][72];
    __shared__ short P_lds[4][16][72];

    int id = blockIdx.x;
    int bb = (id & 7) + 8 * (id >> 9);
    int qt = (id >> 3) & 63;
    int tid = threadIdx.x;
    int w = tid >> 6, lane = tid & 63, li = lane & 15, h4 = lane >> 4;

    int qrow = qt * 64 + w * 16 + li;
    const float* qp = q + ((size_t)bb * SEQ + qrow) * DIM;
    short8 aq[2], aql[2];
    #pragma unroll
    for (int kk = 0; kk < 2; ++kk)
        #pragma unroll
        for (int e = 0; e < 8; ++e) {
            float x = qp[kk * 32 + h4 * 8 + e];
            short h = f2bf(x);
            aq[kk][e] = h; aql[kk][e] = f2bf(x - bf2f(h));
        }

    float m[4], l[4];
    #pragma unroll
    for (int r = 0; r < 4; ++r) { m[r] = -3.0e38f; l[r] = 0.0f; }
    const float* kbase = k + (size_t)bb * SEQ * DIM;
    const float* vbase = v + (size_t)bb * SEQ * DIM;

    for (int ch = 0; ch < NCH; ++ch) {
        __syncthreads();
        const float4* kc = (const float4*)(kbase + (size_t)ch * KVB * DIM);
        #pragma unroll
        for (int j = 0; j < 4; ++j) {
            int f4 = j * 256 + tid; int key = f4 >> 4, d4 = f4 & 15;
            float4 val = kc[f4];
            short4v h4v, l4v;
            h4v[0]=f2bf(val.x); l4v[0]=f2bf(val.x-bf2f(h4v[0]));
            h4v[1]=f2bf(val.y); l4v[1]=f2bf(val.y-bf2f(h4v[1]));
            h4v[2]=f2bf(val.z); l4v[2]=f2bf(val.z-bf2f(h4v[2]));
            h4v[3]=f2bf(val.w); l4v[3]=f2bf(val.w-bf2f(h4v[3]));
            *(short4v*)&K_hi[key][d4*4] = h4v;
            *(short4v*)&K_lo[key][d4*4] = l4v;
        }
        __syncthreads();
        f32x4 s[4];
        #pragma unroll
        for (int nf = 0; nf < 4; ++nf) s[nf] = (f32x4){0.f,0.f,0.f,0.f};
        #pragma unroll
        for (int kk = 0; kk < 2; ++kk)
            #pragma unroll
            for (int nf = 0; nf < 4; ++nf) {
                short8 kbv = *(const short8*)&K_hi[nf*16+li][kk*32+h4*8];
                short8 klv = *(const short8*)&K_lo[nf*16+li][kk*32+h4*8];
                s[nf] = __builtin_amdgcn_mfma_f32_16x16x32_bf16(aq[kk],  kbv, s[nf],0,0,0);
                s[nf] = __builtin_amdgcn_mfma_f32_16x16x32_bf16(aq[kk],  klv, s[nf],0,0,0);
                s[nf] = __builtin_amdgcn_mfma_f32_16x16x32_bf16(aql[kk], kbv, s[nf],0,0,0);
            }
        #pragma unroll
        for (int r = 0; r < 4; ++r) {
            float cmax = fmaxf(fmaxf(s[0][r],s[1][r]), fmaxf(s[2][r],s[3][r]));
            #pragma unroll
            for (int off = 1; off < 16; off <<= 1) cmax = fmaxf(cmax, __shfl_xor(cmax, off));
            float mnew = fmaxf(m[r], cmax);
            float cs = __expf(s[0][r]-mnew)+__expf(s[1][r]-mnew)+__expf(s[2][r]-mnew)+__expf(s[3][r]-mnew);
            #pragma unroll
            for (int off = 1; off < 16; off <<= 1) cs += __shfl_xor(cs, off);
            l[r] = l[r]*__expf(m[r]-mnew) + cs; m[r] = mnew;
        }
    }
    float rl[4];
    #pragma unroll
    for (int r = 0; r < 4; ++r) rl[r] = 1.0f / l[r];

    f32x4 acc[4];
    #pragma unroll
    for (int nf = 0; nf < 4; ++nf) acc[nf] = (f32x4){0.f,0.f,0.f,0.f};
    float* attb = att + ((size_t)bb * SEQ + (size_t)qt * 64 + w * 16) * SEQ;

    for (int ch = 0; ch < NCH; ++ch) {
        __syncthreads();
        const float4* kc = (const float4*)(kbase + (size_t)ch * KVB * DIM);
        #pragma unroll
        for (int j = 0; j < 4; ++j) {
            int f4 = j * 256 + tid; int key = f4 >> 4, d4 = f4 & 15;
            float4 val = kc[f4];
            short4v h4v, l4v;
            h4v[0]=f2bf(val.x); l4v[0]=f2bf(val.x-bf2f(h4v[0]));
            h4v[1]=f2bf(val.y); l4v[1]=f2bf(val.y-bf2f(h4v[1]));
            h4v[2]=f2bf(val.z); l4v[2]=f2bf(val.z-bf2f(h4v[2]));
            h4v[3]=f2bf(val.w); l4v[3]=f2bf(val.w-bf2f(h4v[3]));
            *(short4v*)&K_hi[key][d4*4] = h4v;
            *(short4v*)&K_lo[key][d4*4] = l4v;
        }
        {
            int key = tid & 63, dblk = (tid >> 6) * 16;
            const float* vc = vbase + ((size_t)ch * KVB + key) * DIM + dblk;
            #pragma unroll
            for (int j = 0; j < 4; ++j) {
                float4 val = *(const float4*)(vc + j * 4);
                V_lds[dblk+j*4+0][key]=f2bf(val.x); V_lds[dblk+j*4+1][key]=f2bf(val.y);
                V_lds[dblk+j*4+2][key]=f2bf(val.z); V_lds[dblk+j*4+3][key]=f2bf(val.w);
            }
        }
        __syncthreads();
        f32x4 s[4];
        #pragma unroll
        for (int nf = 0; nf < 4; ++nf) s[nf] = (f32x4){0.f,0.f,0.f,0.f};
        #pragma unroll
        for (int kk = 0; kk < 2; ++kk)
            #pragma unroll
            for (int nf = 0; nf < 4; ++nf) {
                short8 kbv = *(const short8*)&K_hi[nf*16+li][kk*32+h4*8];
                short8 klv = *(const short8*)&K_lo[nf*16+li][kk*32+h4*8];
                s[nf] = __builtin_amdgcn_mfma_f32_16x16x32_bf16(aq[kk],  kbv, s[nf],0,0,0);
                s[nf] = __builtin_amdgcn_mfma_f32_16x16x32_bf16(aq[kk],  klv, s[nf],0,0,0);
                s[nf] = __builtin_amdgcn_mfma_f32_16x16x32_bf16(aql[kk], kbv, s[nf],0,0,0);
            }
        #pragma unroll
        for (int nf = 0; nf < 4; ++nf)
            #pragma unroll
            for (int r = 0; r < 4; ++r) {
                float p = __expf(s[nf][r] - m[r]) * rl[r];
                __builtin_nontemporal_store(p, &attb[(size_t)(4*h4+r)*SEQ + ch*KVB + nf*16 + li]);
                P_lds[w][4*h4+r][nf*16+li] = f2bf(p);
            }
        #pragma unroll
        for (int kk = 0; kk < 2; ++kk) {
            short8 pa = *(const short8*)&P_lds[w][li][kk*32+h4*8];
            #pragma unroll
            for (int nf = 0; nf < 4; ++nf) {
                short8 vbv = *(const short8*)&V_lds[nf*16+li][kk*32+h4*8];
                acc[nf] = __builtin_amdgcn_mfma_f32_16x16x32_bf16(pa, vbv, acc[nf],0,0,0);
            }
        }
    }
    float* ctxb = ctx + ((size_t)bb * SEQ + (size_t)qt * 64 + w * 16) * DIM;
    #pragma unroll
    for (int nf = 0; nf < 4; ++nf)
        #pragma unroll
        for (int r = 0; r < 4; ++r)
            __builtin_nontemporal_store(acc[nf][r], &ctxb[(size_t)(4*h4+r)*DIM + nf*16 + li]);
}

extern "C" void kernel_launch(void* const* d_in, const int* in_sizes, int n_in,
                              void* d_out, int out_size, void* d_ws, size_t ws_size,
                              hipStream_t stream) {
    const float* q = (const float*)d_in[0];
    const float* k = (const float*)d_in[1];
    const float* v = (const float*)d_in[2];
    float* ctx = (float*)d_out;
    float* att = (float*)d_out + (size_t)BATCH * SEQ * DIM;

    const size_t t_el = (size_t)BATCH * EL_B;              // 4,194,304
    const size_t need = 2 * t_el * 2;                      // 16.8 MB

    if (ws_size >= need) {
        _Float16* kh = (_Float16*)d_ws;
        _Float16* vh = kh + t_el;
        preconvert<<<4096, 256, 0, stream>>>(k, v, kh, vh);
        attn_main<<<BATCH * (SEQ / MTILE), 256, 0, stream>>>(q, kh, vh, ctx, att);
    } else {
        attn_fallback<<<BATCH * (SEQ / 64), 256, 0, stream>>>(q, k, v, ctx, att);
    }
}

// Round 14
// 289.751 us; speedup vs baseline: 1.3216x; 1.0110x over previous
//
#include <hip/hip_runtime.h>
#include <hip/hip_bf16.h>

typedef _Float16 half8 __attribute__((ext_vector_type(8)));
typedef _Float16 half4 __attribute__((ext_vector_type(4)));
typedef short short8 __attribute__((ext_vector_type(8)));
typedef short short4v __attribute__((ext_vector_type(4)));
typedef float f32x4 __attribute__((ext_vector_type(4)));

#define BATCH 16
#define SEQ   4096
#define DIM   64
#define KVB   64              // key chunk
#define NCH   (SEQ / KVB)     // 64 chunks
#define NSC   (NCH / 2)       // 32 superchunks (128 keys) for pass 1
#define EL_CH 4096            // elems per chunk per tensor (512 frags * 8)
#define EL_B  (NCH * EL_CH)   // elems per batch per tensor (262144)

__device__ __forceinline__ short f2bf(float f) {
    unsigned u = __builtin_bit_cast(unsigned, f);
    u += 0x7FFF + ((u >> 16) & 1);          // round-to-nearest-even
    return (short)(u >> 16);
}
__device__ __forceinline__ float bf2f(short h) {
    return __builtin_bit_cast(float, (unsigned)((unsigned short)h) << 16);
}

__device__ __forceinline__ void gld16(const void* g, void* l) {
    __builtin_amdgcn_global_load_lds(
        (const __attribute__((address_space(1))) unsigned int*)g,
        (__attribute__((address_space(3))) unsigned int*)l, 16, 0, 0);
}

// ======== pre-kernel: K,V -> fp16 frag-linear (unchanged) ========
// K frag(ch,nf,kk,lane) = K[ch*64 + nf*16 + (lane&15)][kk*32 + (lane>>4)*8 + e]
// V frag(ch,nf,kk,lane) = V[ch*64 + kk*32 + (lane>>4)*8 + e][nf*16 + (lane&15)]
__global__ __launch_bounds__(256) void preconvert(
    const float* __restrict__ k, const float* __restrict__ v,
    _Float16* __restrict__ kh, _Float16* __restrict__ vh)
{
    int f = blockIdx.x * 256 + threadIdx.x;   // 0 .. 2*524288-1
    int lane = f & 63;
    int sub  = (f >> 6) & 7;                  // nf*2 + kk
    int ch   = (f >> 9) & 63;
    int bb   = (f >> 15) & 15;
    int isV  = f >> 19;
    int nf = sub >> 1, kk = sub & 1;
    size_t fo = (size_t)(f & ((1 << 19) - 1)) * 8;

    if (!isV) {
        int key = ch * 64 + nf * 16 + (lane & 15);
        int d0  = kk * 32 + (lane >> 4) * 8;
        const float* src = k + (((size_t)bb * SEQ + key) * DIM + d0);
        half8 h8;
        #pragma unroll
        for (int e = 0; e < 8; ++e) h8[e] = (_Float16)src[e];
        *(half8*)(kh + fo) = h8;
    } else {
        int kr0 = kk * 32 + (lane >> 4) * 8;
        int d   = nf * 16 + (lane & 15);
        const float* src = v + (((size_t)bb * SEQ + ch * 64 + kr0) * DIM + d);
        half8 h8;
        #pragma unroll
        for (int e = 0; e < 8; ++e) h8[e] = (_Float16)src[e * DIM];
        *(half8*)(vh + fo) = h8;
    }
}

// ============================== main kernel ==============================
// r13 skeleton widened to 8 waves / 512 threads per block (128 q-rows).
// Staging per thread halves (1 gld16 per tensor per chunk); 16 waves/CU.
__global__ __launch_bounds__(512, 4) void attn_main(
    const float* __restrict__ q, const _Float16* __restrict__ kh,
    const _Float16* __restrict__ vh, float* __restrict__ ctx,
    float* __restrict__ att)
{
    __shared__ _Float16 KV[2][8192];      // 32 KB pool
                                          // pass1: KV[b] = 128-key K superchunk b
                                          // pass2: KV[0] = K dbuf, KV[1] = V dbuf
    __shared__ _Float16 Ph[8][16][72];    // per-wave P fp16 [q][key] (18 KB)

    int id = blockIdx.x;                  // grid = 512
    int bb = (id & 7) + 8 * (id >> 8);    // XCD-swizzled batch
    int qt = (id >> 3) & 31;              // 32 q-tiles of 128 rows

    int tid = threadIdx.x;
    int w = tid >> 6, lane = tid & 63, li = lane & 15, h4 = lane >> 4;

    // ---- Q B-fragments (fp16): this thread's q-row is qrow (q = li) ----
    int qrow = qt * 128 + w * 16 + li;
    const float* qp = q + ((size_t)bb * SEQ + qrow) * DIM;
    half8 aq[2];
    #pragma unroll
    for (int kk = 0; kk < 2; ++kk)
        #pragma unroll
        for (int e = 0; e < 8; ++e)
            aq[kk][e] = (_Float16)qp[kk * 32 + h4 * 8 + e];

    const _Float16* khb = kh + (size_t)bb * EL_B;
    const _Float16* vvb = vh + (size_t)bb * EL_B;

    // swapped QK^T from a frag-linear LDS base: s[nf][r]=S[q=li][16nf+4h4+r]
    auto qkt = [&](const _Float16* base, f32x4* s) {
        const half8* k8 = (const half8*)base;
        #pragma unroll
        for (int kk = 0; kk < 2; ++kk)
            #pragma unroll
            for (int nf = 0; nf < 4; ++nf)
                s[nf] = __builtin_amdgcn_mfma_f32_16x16x32_f16(
                    k8[(nf * 2 + kk) * 64 + lane], aq[kk], s[nf], 0, 0, 0);
    };

    // ========== pass 1: l = sum exp(s), 128-key superchunks ==========
    float ll = 0.f;

    auto stage_sc = [&](int buf, int sc) {        // 16 KB superchunk, 2 gld16
        const _Float16* g = khb + (size_t)sc * (2 * EL_CH) + tid * 8;
        gld16(g,        &KV[buf][w * 512]);
        gld16(g + 4096, &KV[buf][4096 + w * 512]);
    };

    stage_sc(0, 0);
    for (int sc = 0; sc < NSC; ++sc) {
        int buf = sc & 1;
        if (sc + 1 < NSC) {
            stage_sc(buf ^ 1, sc + 1);
            asm volatile("s_waitcnt vmcnt(2)" ::: "memory");
        } else {
            asm volatile("s_waitcnt vmcnt(0)" ::: "memory");
        }
        __builtin_amdgcn_s_barrier();
        asm volatile("" ::: "memory");

        #pragma unroll
        for (int c2 = 0; c2 < 2; ++c2) {
            f32x4 s[4];
            #pragma unroll
            for (int nf = 0; nf < 4; ++nf) s[nf] = (f32x4){0.f, 0.f, 0.f, 0.f};
            qkt(&KV[buf][c2 * EL_CH], s);
            float a = 0.f;
            #pragma unroll
            for (int nf = 0; nf < 4; ++nf)
                #pragma unroll
                for (int r = 0; r < 4; ++r)
                    a += __expf(s[nf][r]);
            ll += a;
        }

        asm volatile("" ::: "memory");
        __builtin_amdgcn_s_barrier();
    }

    // reduce over the 4 lanes sharing this q-row (h4 group), invert
    ll += __shfl_xor(ll, 16);
    ll += __shfl_xor(ll, 32);
    float rl = 1.0f / ll;

    // ========== pass 2: p = exp(s)*rl; Ph 256B att stores; PV fp16 =========
    f32x4 acc[4];
    #pragma unroll
    for (int nf = 0; nf < 4; ++nf) acc[nf] = (f32x4){0.f, 0.f, 0.f, 0.f};

    float* attb = att + ((size_t)bb * SEQ + (size_t)qt * 128 + w * 16) * SEQ;

    auto stage_k = [&](int buf, int ch) {         // 1 gld16
        const _Float16* g = khb + (size_t)ch * EL_CH + tid * 8;
        gld16(g, &KV[0][buf * EL_CH + w * 512]);
    };
    auto stage_v = [&](int buf, int ch) {         // 1 gld16
        const _Float16* g = vvb + (size_t)ch * EL_CH + tid * 8;
        gld16(g, &KV[1][buf * EL_CH + w * 512]);
    };

    stage_k(0, 0); stage_v(0, 0);
    for (int ch = 0; ch < NCH; ++ch) {
        int buf = ch & 1;
        if (ch + 1 < NCH) {
            stage_k(buf ^ 1, ch + 1);
            stage_v(buf ^ 1, ch + 1);
            // queue: [2 loads cur][4 stores prev][2 loads next]
            if (ch == 0) asm volatile("s_waitcnt vmcnt(2)" ::: "memory");
            else         asm volatile("s_waitcnt vmcnt(6)" ::: "memory");
        } else {
            // queue: [2 loads cur][4 stores prev]
            asm volatile("s_waitcnt vmcnt(4)" ::: "memory");
        }
        __builtin_amdgcn_s_barrier();
        asm volatile("" ::: "memory");

        f32x4 s[4];
        #pragma unroll
        for (int nf = 0; nf < 4; ++nf) s[nf] = (f32x4){0.f, 0.f, 0.f, 0.f};
        qkt(&KV[0][buf * EL_CH], s);

        // p -> Ph[q=li][key]: 4 consecutive keys per write -> ds_write_b64
        #pragma unroll
        for (int nf = 0; nf < 4; ++nf) {
            half4 p4;
            #pragma unroll
            for (int r = 0; r < 4; ++r)
                p4[r] = (_Float16)(__expf(s[nf][r]) * rl);
            *(half4*)&Ph[w][li][nf * 16 + h4 * 4] = p4;
        }

        // att stores, 16-lane contiguous: 256B runs (proven; >=128B rule)
        #pragma unroll
        for (int j = 0; j < 4; ++j) {
            int row = j * 4 + h4;
            half4 ph = *(const half4*)&Ph[w][row][li * 4];
            f32x4 pv = { (float)ph[0], (float)ph[1], (float)ph[2], (float)ph[3] };
            __builtin_nontemporal_store(
                pv, (f32x4*)(attb + (size_t)row * SEQ + ch * KVB + li * 4));
        }

        // PV (fp16): acc[q][d] += P[q][key] * V[key][d]
        const half8* v8 = (const half8*)&KV[1][buf * EL_CH];
        #pragma unroll
        for (int kk = 0; kk < 2; ++kk) {
            half8 pa = *(const half8*)&Ph[w][li][kk * 32 + h4 * 8];
            #pragma unroll
            for (int nf = 0; nf < 4; ++nf)
                acc[nf] = __builtin_amdgcn_mfma_f32_16x16x32_f16(
                    pa, v8[(nf * 2 + kk) * 64 + lane], acc[nf], 0, 0, 0);
        }

        asm volatile("" ::: "memory");
        __builtin_amdgcn_s_barrier();
    }

    float* ctxb = ctx + ((size_t)bb * SEQ + (size_t)qt * 128 + w * 16) * DIM;
    #pragma unroll
    for (int nf = 0; nf < 4; ++nf)
        #pragma unroll
        for (int r = 0; r < 4; ++r)
            __builtin_nontemporal_store(
                acc[nf][r], &ctxb[(size_t)(4 * h4 + r) * DIM + nf * 16 + li]);
}

// ===================== fallback (round-2 kernel, proven) =====================
__global__ __launch_bounds__(256) void attn_fallback(
    const float* __restrict__ q, const float* __restrict__ k,
    const float* __restrict__ v, float* __restrict__ ctx,
    float* __restrict__ att)
{
    __shared__ short K_hi[KVB][72];
    __shared__ short K_lo[KVB][72];
    __shared__ short V_lds[DIM][72];
    __shared__ short P_lds[4][16][72];

    int id = blockIdx.x;
    int bb = (id & 7) + 8 * (id >> 9);
    int qt = (id >> 3) & 63;
    int tid = threadIdx.x;
    int w = tid >> 6, lane = tid & 63, li = lane & 15, h4 = lane >> 4;

    int qrow = qt * 64 + w * 16 + li;
    const float* qp = q + ((size_t)bb * SEQ + qrow) * DIM;
    short8 aq[2], aql[2];
    #pragma unroll
    for (int kk = 0; kk < 2; ++kk)
        #pragma unroll
        for (int e = 0; e < 8; ++e) {
            float x = qp[kk * 32 + h4 * 8 + e];
            short h = f2bf(x);
            aq[kk][e] = h; aql[kk][e] = f2bf(x - bf2f(h));
        }

    float m[4], l[4];
    #pragma unroll
    for (int r = 0; r < 4; ++r) { m[r] = -3.0e38f; l[r] = 0.0f; }
    const float* kbase = k + (size_t)bb * SEQ * DIM;
    const float* vbase = v + (size_t)bb * SEQ * DIM;

    for (int ch = 0; ch < NCH; ++ch) {
        __syncthreads();
        const float4* kc = (const float4*)(kbase + (size_t)ch * KVB * DIM);
        #pragma unroll
        for (int j = 0; j < 4; ++j) {
            int f4 = j * 256 + tid; int key = f4 >> 4, d4 = f4 & 15;
            float4 val = kc[f4];
            short4v h4v, l4v;
            h4v[0]=f2bf(val.x); l4v[0]=f2bf(val.x-bf2f(h4v[0]));
            h4v[1]=f2bf(val.y); l4v[1]=f2bf(val.y-bf2f(h4v[1]));
            h4v[2]=f2bf(val.z); l4v[2]=f2bf(val.z-bf2f(h4v[2]));
            h4v[3]=f2bf(val.w); l4v[3]=f2bf(val.w-bf2f(h4v[3]));
            *(short4v*)&K_hi[key][d4*4] = h4v;
            *(short4v*)&K_lo[key][d4*4] = l4v;
        }
        __syncthreads();
        f32x4 s[4];
        #pragma unroll
        for (int nf = 0; nf < 4; ++nf) s[nf] = (f32x4){0.f,0.f,0.f,0.f};
        #pragma unroll
        for (int kk = 0; kk < 2; ++kk)
            #pragma unroll
            for (int nf = 0; nf < 4; ++nf) {
                short8 kbv = *(const short8*)&K_hi[nf*16+li][kk*32+h4*8];
                short8 klv = *(const short8*)&K_lo[nf*16+li][kk*32+h4*8];
                s[nf] = __builtin_amdgcn_mfma_f32_16x16x32_bf16(aq[kk],  kbv, s[nf],0,0,0);
                s[nf] = __builtin_amdgcn_mfma_f32_16x16x32_bf16(aq[kk],  klv, s[nf],0,0,0);
                s[nf] = __builtin_amdgcn_mfma_f32_16x16x32_bf16(aql[kk], kbv, s[nf],0,0,0);
            }
        #pragma unroll
        for (int r = 0; r < 4; ++r) {
            float cmax = fmaxf(fmaxf(s[0][r],s[1][r]), fmaxf(s[2][r],s[3][r]));
            #pragma unroll
            for (int off = 1; off < 16; off <<= 1) cmax = fmaxf(cmax, __shfl_xor(cmax, off));
            float mnew = fmaxf(m[r], cmax);
            float cs = __expf(s[0][r]-mnew)+__expf(s[1][r]-mnew)+__expf(s[2][r]-mnew)+__expf(s[3][r]-mnew);
            #pragma unroll
            for (int off = 1; off < 16; off <<= 1) cs += __shfl_xor(cs, off);
            l[r] = l[r]*__expf(m[r]-mnew) + cs; m[r] = mnew;
        }
    }
    float rl[4];
    #pragma unroll
    for (int r = 0; r < 4; ++r) rl[r] = 1.0f / l[r];

    f32x4 acc[4];
    #pragma unroll
    for (int nf = 0; nf < 4; ++nf) acc[nf] = (f32x4){0.f,0.f,0.f,0.f};
    float* attb = att + ((size_t)bb * SEQ + (size_t)qt * 64 + w * 16) * SEQ;

    for (int ch = 0; ch < NCH; ++ch) {
        __syncthreads();
        const float4* kc = (const float4*)(kbase + (size_t)ch * KVB * DIM);
        #pragma unroll
        for (int j = 0; j < 4; ++j) {
            int f4 = j * 256 + tid; int key = f4 >> 4, d4 = f4 & 15;
            float4 val = kc[f4];
            short4v h4v, l4v;
            h4v[0]=f2bf(val.x); l4v[0]=f2bf(val.x-bf2f(h4v[0]));
            h4v[1]=f2bf(val.y); l4v[1]=f2bf(val.y-bf2f(h4v[1]));
            h4v[2]=f2bf(val.z); l4v[2]=f2bf(val.z-bf2f(h4v[2]));
            h4v[3]=f2bf(val.w); l4v[3]=f2bf(val.w-bf2f(h4v[3]));
            *(short4v*)&K_hi[key][d4*4] = h4v;
            *(short4v*)&K_lo[key][d4*4] = l4v;
        }
        {
            int key = tid & 63, dblk = (tid >> 6) * 16;
            const float* vc = vbase + ((size_t)ch * KVB + key) * DIM + dblk;
            #pragma unroll
            for (int j = 0; j < 4; ++j) {
                float4 val = *(const float4*)(vc + j * 4);
                V_lds[dblk+j*4+0][key]=f2bf(val.x); V_lds[dblk+j*4+1][key]=f2bf(val.y);
                V_lds[dblk+j*4+2][key]=f2bf(val.z); V_lds[dblk+j*4+3][key]=f2bf(val.w);
            }
        }
        __syncthreads();
        f32x4 s[4];
        #pragma unroll
        for (int nf = 0; nf < 4; ++nf) s[nf] = (f32x4){0.f,0.f,0.f,0.f};
        #pragma unroll
        for (int kk = 0; kk < 2; ++kk)
            #pragma unroll
            for (int nf = 0; nf < 4; ++nf) {
                short8 kbv = *(const short8*)&K_hi[nf*16+li][kk*32+h4*8];
                short8 klv = *(const short8*)&K_lo[nf*16+li][kk*32+h4*8];
                s[nf] = __builtin_amdgcn_mfma_f32_16x16x32_bf16(aq[kk],  kbv, s[nf],0,0,0);
                s[nf] = __builtin_amdgcn_mfma_f32_16x16x32_bf16(aq[kk],  klv, s[nf],0,0,0);
                s[nf] = __builtin_amdgcn_mfma_f32_16x16x32_bf16(aql[kk], kbv, s[nf],0,0,0);
            }
        #pragma unroll
        for (int nf = 0; nf < 4; ++nf)
            #pragma unroll
            for (int r = 0; r < 4; ++r) {
                float p = __expf(s[nf][r] - m[r]) * rl[r];
                __builtin_nontemporal_store(p, &attb[(size_t)(4*h4+r)*SEQ + ch*KVB + nf*16 + li]);
                P_lds[w][4*h4+r][nf*16+li] = f2bf(p);
            }
        #pragma unroll
        for (int kk = 0; kk < 2; ++kk) {
            short8 pa = *(const short8*)&P_lds[w][li][kk*32+h4*8];
            #pragma unroll
            for (int nf = 0; nf < 4; ++nf) {
                short8 vbv = *(const short8*)&V_lds[nf*16+li][kk*32+h4*8];
                acc[nf] = __builtin_amdgcn_mfma_f32_16x16x32_bf16(pa, vbv, acc[nf],0,0,0);
            }
        }
    }
    float* ctxb = ctx + ((size_t)bb * SEQ + (size_t)qt * 64 + w * 16) * DIM;
    #pragma unroll
    for (int nf = 0; nf < 4; ++nf)
        #pragma unroll
        for (int r = 0; r < 4; ++r)
            __builtin_nontemporal_store(acc[nf][r], &ctxb[(size_t)(4*h4+r)*DIM + nf*16 + li]);
}

extern "C" void kernel_launch(void* const* d_in, const int* in_sizes, int n_in,
                              void* d_out, int out_size, void* d_ws, size_t ws_size,
                              hipStream_t stream) {
    const float* q = (const float*)d_in[0];
    const float* k = (const float*)d_in[1];
    const float* v = (const float*)d_in[2];
    float* ctx = (float*)d_out;
    float* att = (float*)d_out + (size_t)BATCH * SEQ * DIM;

    const size_t t_el = (size_t)BATCH * EL_B;              // 4,194,304
    const size_t need = 2 * t_el * 2;                      // 16.8 MB

    if (ws_size >= need) {
        _Float16* kh = (_Float16*)d_ws;
        _Float16* vh = kh + t_el;
        preconvert<<<4096, 256, 0, stream>>>(k, v, kh, vh);
        attn_main<<<512, 512, 0, stream>>>(q, kh, vh, ctx, att);
    } else {
        attn_fallback<<<BATCH * (SEQ / 64), 256, 0, stream>>>(q, k, v, ctx, att);
    }
}

// Round 15
// 282.082 us; speedup vs baseline: 1.3575x; 1.0272x over previous
//
#include <hip/hip_runtime.h>
#include <hip/hip_bf16.h>

typedef _Float16 half8 __attribute__((ext_vector_type(8)));
typedef _Float16 half4 __attribute__((ext_vector_type(4)));
typedef short short8 __attribute__((ext_vector_type(8)));
typedef short short4v __attribute__((ext_vector_type(4)));
typedef float f32x4 __attribute__((ext_vector_type(4)));

#define BATCH 16
#define SEQ   4096
#define DIM   64
#define KVB   64              // base key chunk (frag-linear unit)
#define NCH   (SEQ / KVB)     // 64 chunks
#define NSC   (NCH / 2)       // 32 superchunks (128 keys) for BOTH passes
#define EL_CH 4096            // elems per 64-key chunk per tensor
#define EL_SC 8192            // elems per 128-key superchunk per tensor
#define EL_B  (NCH * EL_CH)   // elems per batch per tensor (262144)
#define PHS   136             // Ph row stride in halves (128 + 8 pad, 272B)

__device__ __forceinline__ short f2bf(float f) {
    unsigned u = __builtin_bit_cast(unsigned, f);
    u += 0x7FFF + ((u >> 16) & 1);          // round-to-nearest-even
    return (short)(u >> 16);
}
__device__ __forceinline__ float bf2f(short h) {
    return __builtin_bit_cast(float, (unsigned)((unsigned short)h) << 16);
}

__device__ __forceinline__ void gld16(const void* g, void* l) {
    __builtin_amdgcn_global_load_lds(
        (const __attribute__((address_space(1))) unsigned int*)g,
        (__attribute__((address_space(3))) unsigned int*)l, 16, 0, 0);
}

// ======== pre-kernel: K,V -> fp16 frag-linear (unchanged) ========
// K frag(ch,nf,kk,lane) = K[ch*64 + nf*16 + (lane&15)][kk*32 + (lane>>4)*8 + e]
// V frag(ch,nf,kk,lane) = V[ch*64 + kk*32 + (lane>>4)*8 + e][nf*16 + (lane&15)]
__global__ __launch_bounds__(256) void preconvert(
    const float* __restrict__ k, const float* __restrict__ v,
    _Float16* __restrict__ kh, _Float16* __restrict__ vh)
{
    int f = blockIdx.x * 256 + threadIdx.x;   // 0 .. 2*524288-1
    int lane = f & 63;
    int sub  = (f >> 6) & 7;                  // nf*2 + kk
    int ch   = (f >> 9) & 63;
    int bb   = (f >> 15) & 15;
    int isV  = f >> 19;
    int nf = sub >> 1, kk = sub & 1;
    size_t fo = (size_t)(f & ((1 << 19) - 1)) * 8;

    if (!isV) {
        int key = ch * 64 + nf * 16 + (lane & 15);
        int d0  = kk * 32 + (lane >> 4) * 8;
        const float* src = k + (((size_t)bb * SEQ + key) * DIM + d0);
        half8 h8;
        #pragma unroll
        for (int e = 0; e < 8; ++e) h8[e] = (_Float16)src[e];
        *(half8*)(kh + fo) = h8;
    } else {
        int kr0 = kk * 32 + (lane >> 4) * 8;
        int d   = nf * 16 + (lane & 15);
        const float* src = v + (((size_t)bb * SEQ + ch * 64 + kr0) * DIM + d);
        half8 h8;
        #pragma unroll
        for (int e = 0; e < 8; ++e) h8[e] = (_Float16)src[e * DIM];
        *(half8*)(vh + fo) = h8;
    }
}

// ============================== main kernel ==============================
// r14 skeleton; pass 2 now iterates 128-key superchunks so each att row gets
// 512B of contiguous stores per iteration (2x better HBM page locality).
__global__ __launch_bounds__(512, 2) void attn_main(
    const float* __restrict__ q, const _Float16* __restrict__ kh,
    const _Float16* __restrict__ vh, float* __restrict__ ctx,
    float* __restrict__ att)
{
    __shared__ __align__(16) _Float16 Kst[2][EL_SC];   // 32 KB (2 x 128-key K)
    __shared__ __align__(16) _Float16 Vst[2][EL_SC];   // 32 KB (2 x 128-key V)
    __shared__ __align__(16) _Float16 Ph[8][16][PHS];  // 34 KB, P[q][key 0..127]

    int id = blockIdx.x;                  // grid = 512
    int bb = (id & 7) + 8 * (id >> 8);    // XCD-swizzled batch
    int qt = (id >> 3) & 31;              // 32 q-tiles of 128 rows

    int tid = threadIdx.x;
    int w = tid >> 6, lane = tid & 63, li = lane & 15, h4 = lane >> 4;

    // ---- Q B-fragments (fp16): this thread's q-row is qrow (q = li) ----
    int qrow = qt * 128 + w * 16 + li;
    const float* qp = q + ((size_t)bb * SEQ + qrow) * DIM;
    half8 aq[2];
    #pragma unroll
    for (int kk = 0; kk < 2; ++kk)
        #pragma unroll
        for (int e = 0; e < 8; ++e)
            aq[kk][e] = (_Float16)qp[kk * 32 + h4 * 8 + e];

    const _Float16* khb = kh + (size_t)bb * EL_B;
    const _Float16* vvb = vh + (size_t)bb * EL_B;

    // swapped QK^T from a frag-linear LDS base: s[nf][r]=S[q=li][16nf+4h4+r]
    auto qkt = [&](const _Float16* base, f32x4* s) {
        const half8* k8 = (const half8*)base;
        #pragma unroll
        for (int kk = 0; kk < 2; ++kk)
            #pragma unroll
            for (int nf = 0; nf < 4; ++nf)
                s[nf] = __builtin_amdgcn_mfma_f32_16x16x32_f16(
                    k8[(nf * 2 + kk) * 64 + lane], aq[kk], s[nf], 0, 0, 0);
    };

    // ========== pass 1: l = sum exp(s), 128-key superchunks ==========
    float ll = 0.f;

    auto stage_sc = [&](int buf, int sc) {        // 16 KB K superchunk, 2 gld16
        const _Float16* g = khb + (size_t)sc * EL_SC + tid * 8;
        gld16(g,        &Kst[buf][w * 512]);
        gld16(g + 4096, &Kst[buf][4096 + w * 512]);
    };

    stage_sc(0, 0);
    for (int sc = 0; sc < NSC; ++sc) {
        int buf = sc & 1;
        if (sc + 1 < NSC) {
            stage_sc(buf ^ 1, sc + 1);
            asm volatile("s_waitcnt vmcnt(2)" ::: "memory");
        } else {
            asm volatile("s_waitcnt vmcnt(0)" ::: "memory");
        }
        __builtin_amdgcn_s_barrier();
        asm volatile("" ::: "memory");

        #pragma unroll
        for (int c2 = 0; c2 < 2; ++c2) {
            f32x4 s[4];
            #pragma unroll
            for (int nf = 0; nf < 4; ++nf) s[nf] = (f32x4){0.f, 0.f, 0.f, 0.f};
            qkt(&Kst[buf][c2 * EL_CH], s);
            float a = 0.f;
            #pragma unroll
            for (int nf = 0; nf < 4; ++nf)
                #pragma unroll
                for (int r = 0; r < 4; ++r)
                    a += __expf(s[nf][r]);
            ll += a;
        }

        asm volatile("" ::: "memory");
        __builtin_amdgcn_s_barrier();
    }

    // reduce over the 4 lanes sharing this q-row (h4 group), invert
    ll += __shfl_xor(ll, 16);
    ll += __shfl_xor(ll, 32);
    float rl = 1.0f / ll;

    // ========== pass 2: 128-key superchunks; 512B/row store runs ==========
    f32x4 acc[4];
    #pragma unroll
    for (int nf = 0; nf < 4; ++nf) acc[nf] = (f32x4){0.f, 0.f, 0.f, 0.f};

    float* attb = att + ((size_t)bb * SEQ + (size_t)qt * 128 + w * 16) * SEQ;

    auto stage_k2 = [&](int buf, int sc) {        // 2 gld16
        const _Float16* g = khb + (size_t)sc * EL_SC + tid * 8;
        gld16(g,        &Kst[buf][w * 512]);
        gld16(g + 4096, &Kst[buf][4096 + w * 512]);
    };
    auto stage_v2 = [&](int buf, int sc) {        // 2 gld16
        const _Float16* g = vvb + (size_t)sc * EL_SC + tid * 8;
        gld16(g,        &Vst[buf][w * 512]);
        gld16(g + 4096, &Vst[buf][4096 + w * 512]);
    };

    stage_k2(0, 0); stage_v2(0, 0);
    for (int sc = 0; sc < NSC; ++sc) {
        int buf = sc & 1;
        if (sc + 1 < NSC) {
            stage_k2(buf ^ 1, sc + 1);
            stage_v2(buf ^ 1, sc + 1);
            // queue: [4 loads cur][8 stores prev][4 loads next]
            if (sc == 0) asm volatile("s_waitcnt vmcnt(4)"  ::: "memory");
            else         asm volatile("s_waitcnt vmcnt(12)" ::: "memory");
        } else {
            // queue: [4 loads cur][8 stores prev]
            asm volatile("s_waitcnt vmcnt(8)" ::: "memory");
        }
        __builtin_amdgcn_s_barrier();
        asm volatile("" ::: "memory");

        // QK^T for both 64-key halves
        f32x4 sA[4], sB[4];
        #pragma unroll
        for (int nf = 0; nf < 4; ++nf) {
            sA[nf] = (f32x4){0.f, 0.f, 0.f, 0.f};
            sB[nf] = (f32x4){0.f, 0.f, 0.f, 0.f};
        }
        qkt(&Kst[buf][0],     sA);
        qkt(&Kst[buf][EL_CH], sB);

        // p -> Ph[q=li][key 0..127]: ds_write_b64 per 4-key group
        #pragma unroll
        for (int nf = 0; nf < 4; ++nf) {
            half4 pa, pb;
            #pragma unroll
            for (int r = 0; r < 4; ++r) {
                pa[r] = (_Float16)(__expf(sA[nf][r]) * rl);
                pb[r] = (_Float16)(__expf(sB[nf][r]) * rl);
            }
            *(half4*)&Ph[w][li][nf * 16 + h4 * 4]      = pa;
            *(half4*)&Ph[w][li][64 + nf * 16 + h4 * 4] = pb;
        }

        // att stores: per row, two back-to-back f32x4 (16 lanes each) cover
        // 512B contiguous -> better HBM page locality
        #pragma unroll
        for (int j = 0; j < 4; ++j) {
            int row = j * 4 + h4;
            half4 pa = *(const half4*)&Ph[w][row][li * 4];
            half4 pb = *(const half4*)&Ph[w][row][64 + li * 4];
            f32x4 va = { (float)pa[0], (float)pa[1], (float)pa[2], (float)pa[3] };
            f32x4 vb = { (float)pb[0], (float)pb[1], (float)pb[2], (float)pb[3] };
            float* dst = attb + (size_t)row * SEQ + sc * 128;
            __builtin_nontemporal_store(va, (f32x4*)(dst + li * 4));
            __builtin_nontemporal_store(vb, (f32x4*)(dst + 64 + li * 4));
        }

        // PV over 128 keys: 16 MFMA; k-slice kk covers keys kk*32..kk*32+31
        const half8* v8 = (const half8*)&Vst[buf][0];
        #pragma unroll
        for (int kk = 0; kk < 4; ++kk) {
            half8 pa = *(const half8*)&Ph[w][li][kk * 32 + h4 * 8];
            #pragma unroll
            for (int nf = 0; nf < 4; ++nf)
                acc[nf] = __builtin_amdgcn_mfma_f32_16x16x32_f16(
                    pa, v8[(kk >> 1) * 512 + (nf * 2 + (kk & 1)) * 64 + lane],
                    acc[nf], 0, 0, 0);
        }

        asm volatile("" ::: "memory");
        __builtin_amdgcn_s_barrier();
    }

    float* ctxb = ctx + ((size_t)bb * SEQ + (size_t)qt * 128 + w * 16) * DIM;
    #pragma unroll
    for (int nf = 0; nf < 4; ++nf)
        #pragma unroll
        for (int r = 0; r < 4; ++r)
            __builtin_nontemporal_store(
                acc[nf][r], &ctxb[(size_t)(4 * h4 + r) * DIM + nf * 16 + li]);
}

// ===================== fallback (round-2 kernel, proven) =====================
__global__ __launch_bounds__(256) void attn_fallback(
    const float* __restrict__ q, const float* __restrict__ k,
    const float* __restrict__ v, float* __restrict__ ctx,
    float* __restrict__ att)
{
    __shared__ short K_hi[KVB][72];
    __shared__ short K_lo[KVB][72];
    __shared__ short V_lds[DIM][72];
    __shared__ short P_lds[4][16][72];

    int id = blockIdx.x;
    int bb = (id & 7) + 8 * (id >> 9);
    int qt = (id >> 3) & 63;
    int tid = threadIdx.x;
    int w = tid >> 6, lane = tid & 63, li = lane & 15, h4 = lane >> 4;

    int qrow = qt * 64 + w * 16 + li;
    const float* qp = q + ((size_t)bb * SEQ + qrow) * DIM;
    short8 aq[2], aql[2];
    #pragma unroll
    for (int kk = 0; kk < 2; ++kk)
        #pragma unroll
        for (int e = 0; e < 8; ++e) {
            float x = qp[kk * 32 + h4 * 8 + e];
            short h = f2bf(x);
            aq[kk][e] = h; aql[kk][e] = f2bf(x - bf2f(h));
        }

    float m[4], l[4];
    #pragma unroll
    for (int r = 0; r < 4; ++r) { m[r] = -3.0e38f; l[r] = 0.0f; }
    const float* kbase = k + (size_t)bb * SEQ * DIM;
    const float* vbase = v + (size_t)bb * SEQ * DIM;

    for (int ch = 0; ch < NCH; ++ch) {
        __syncthreads();
        const float4* kc = (const float4*)(kbase + (size_t)ch * KVB * DIM);
        #pragma unroll
        for (int j = 0; j < 4; ++j) {
            int f4 = j * 256 + tid; int key = f4 >> 4, d4 = f4 & 15;
            float4 val = kc[f4];
            short4v h4v, l4v;
            h4v[0]=f2bf(val.x); l4v[0]=f2bf(val.x-bf2f(h4v[0]));
            h4v[1]=f2bf(val.y); l4v[1]=f2bf(val.y-bf2f(h4v[1]));
            h4v[2]=f2bf(val.z); l4v[2]=f2bf(val.z-bf2f(h4v[2]));
            h4v[3]=f2bf(val.w); l4v[3]=f2bf(val.w-bf2f(h4v[3]));
            *(short4v*)&K_hi[key][d4*4] = h4v;
            *(short4v*)&K_lo[key][d4*4] = l4v;
        }
        __syncthreads();
        f32x4 s[4];
        #pragma unroll
        for (int nf = 0; nf < 4; ++nf) s[nf] = (f32x4){0.f,0.f,0.f,0.f};
        #pragma unroll
        for (int kk = 0; kk < 2; ++kk)
            #pragma unroll
            for (int nf = 0; nf < 4; ++nf) {
                short8 kbv = *(const short8*)&K_hi[nf*16+li][kk*32+h4*8];
                short8 klv = *(const short8*)&K_lo[nf*16+li][kk*32+h4*8];
                s[nf] = __builtin_amdgcn_mfma_f32_16x16x32_bf16(aq[kk],  kbv, s[nf],0,0,0);
                s[nf] = __builtin_amdgcn_mfma_f32_16x16x32_bf16(aq[kk],  klv, s[nf],0,0,0);
                s[nf] = __builtin_amdgcn_mfma_f32_16x16x32_bf16(aql[kk], kbv, s[nf],0,0,0);
            }
        #pragma unroll
        for (int r = 0; r < 4; ++r) {
            float cmax = fmaxf(fmaxf(s[0][r],s[1][r]), fmaxf(s[2][r],s[3][r]));
            #pragma unroll
            for (int off = 1; off < 16; off <<= 1) cmax = fmaxf(cmax, __shfl_xor(cmax, off));
            float mnew = fmaxf(m[r], cmax);
            float cs = __expf(s[0][r]-mnew)+__expf(s[1][r]-mnew)+__expf(s[2][r]-mnew)+__expf(s[3][r]-mnew);
            #pragma unroll
            for (int off = 1; off < 16; off <<= 1) cs += __shfl_xor(cs, off);
            l[r] = l[r]*__expf(m[r]-mnew) + cs; m[r] = mnew;
        }
    }
    float rl[4];
    #pragma unroll
    for (int r = 0; r < 4; ++r) rl[r] = 1.0f / l[r];

    f32x4 acc[4];
    #pragma unroll
    for (int nf = 0; nf < 4; ++nf) acc[nf] = (f32x4){0.f,0.f,0.f,0.f};
    float* attb = att + ((size_t)bb * SEQ + (size_t)qt * 64 + w * 16) * SEQ;

    for (int ch = 0; ch < NCH; ++ch) {
        __syncthreads();
        const float4* kc = (const float4*)(kbase + (size_t)ch * KVB * DIM);
        #pragma unroll
        for (int j = 0; j < 4; ++j) {
            int f4 = j * 256 + tid; int key = f4 >> 4, d4 = f4 & 15;
            float4 val = kc[f4];
            short4v h4v, l4v;
            h4v[0]=f2bf(val.x); l4v[0]=f2bf(val.x-bf2f(h4v[0]));
            h4v[1]=f2bf(val.y); l4v[1]=f2bf(val.y-bf2f(h4v[1]));
            h4v[2]=f2bf(val.z); l4v[2]=f2bf(val.z-bf2f(h4v[2]));
            h4v[3]=f2bf(val.w); l4v[3]=f2bf(val.w-bf2f(h4v[3]));
            *(short4v*)&K_hi[key][d4*4] = h4v;
            *(short4v*)&K_lo[key][d4*4] = l4v;
        }
        {
            int key = tid & 63, dblk = (tid >> 6) * 16;
            const float* vc = vbase + ((size_t)ch * KVB + key) * DIM + dblk;
            #pragma unroll
            for (int j = 0; j < 4; ++j) {
                float4 val = *(const float4*)(vc + j * 4);
                V_lds[dblk+j*4+0][key]=f2bf(val.x); V_lds[dblk+j*4+1][key]=f2bf(val.y);
                V_lds[dblk+j*4+2][key]=f2bf(val.z); V_lds[dblk+j*4+3][key]=f2bf(val.w);
            }
        }
        __syncthreads();
        f32x4 s[4];
        #pragma unroll
        for (int nf = 0; nf < 4; ++nf) s[nf] = (f32x4){0.f,0.f,0.f,0.f};
        #pragma unroll
        for (int kk = 0; kk < 2; ++kk)
            #pragma unroll
            for (int nf = 0; nf < 4; ++nf) {
                short8 kbv = *(const short8*)&K_hi[nf*16+li][kk*32+h4*8];
                short8 klv = *(const short8*)&K_lo[nf*16+li][kk*32+h4*8];
                s[nf] = __builtin_amdgcn_mfma_f32_16x16x32_bf16(aq[kk],  kbv, s[nf],0,0,0);
                s[nf] = __builtin_amdgcn_mfma_f32_16x16x32_bf16(aq[kk],  klv, s[nf],0,0,0);
                s[nf] = __builtin_amdgcn_mfma_f32_16x16x32_bf16(aql[kk], kbv, s[nf],0,0,0);
            }
        #pragma unroll
        for (int nf = 0; nf < 4; ++nf)
            #pragma unroll
            for (int r = 0; r < 4; ++r) {
                float p = __expf(s[nf][r] - m[r]) * rl[r];
                __builtin_nontemporal_store(p, &attb[(size_t)(4*h4+r)*SEQ + ch*KVB + nf*16 + li]);
                P_lds[w][4*h4+r][nf*16+li] = f2bf(p);
            }
        #pragma unroll
        for (int kk = 0; kk < 2; ++kk) {
            short8 pa = *(const short8*)&P_lds[w][li][kk*32+h4*8];
            #pragma unroll
            for (int nf = 0; nf < 4; ++nf) {
                short8 vbv = *(const short8*)&V_lds[nf*16+li][kk*32+h4*8];
                acc[nf] = __builtin_amdgcn_mfma_f32_16x16x32_bf16(pa, vbv, acc[nf],0,0,0);
            }
        }
    }
    float* ctxb = ctx + ((size_t)bb * SEQ + (size_t)qt * 64 + w * 16) * DIM;
    #pragma unroll
    for (int nf = 0; nf < 4; ++nf)
        #pragma unroll
        for (int r = 0; r < 4; ++r)
            __builtin_nontemporal_store(acc[nf][r], &ctxb[(size_t)(4*h4+r)*DIM + nf*16 + li]);
}

extern "C" void kernel_launch(void* const* d_in, const int* in_sizes, int n_in,
                              void* d_out, int out_size, void* d_ws, size_t ws_size,
                              hipStream_t stream) {
    const float* q = (const float*)d_in[0];
    const float* k = (const float*)d_in[1];
    const float* v = (const float*)d_in[2];
    float* ctx = (float*)d_out;
    float* att = (float*)d_out + (size_t)BATCH * SEQ * DIM;

    const size_t t_el = (size_t)BATCH * EL_B;              // 4,194,304
    const size_t need = 2 * t_el * 2;                      // 16.8 MB

    if (ws_size >= need) {
        _Float16* kh = (_Float16*)d_ws;
        _Float16* vh = kh + t_el;
        preconvert<<<4096, 256, 0, stream>>>(k, v, kh, vh);
        attn_main<<<512, 512, 0, stream>>>(q, kh, vh, ctx, att);
    } else {
        attn_fallback<<<BATCH * (SEQ / 64), 256, 0, stream>>>(q, k, v, ctx, att);
    }
}

// Round 16
// 261.796 us; speedup vs baseline: 1.4627x; 1.0775x over previous
//
#include <hip/hip_runtime.h>
#include <hip/hip_bf16.h>

typedef _Float16 half8 __attribute__((ext_vector_type(8)));
typedef _Float16 half4 __attribute__((ext_vector_type(4)));
typedef short short8 __attribute__((ext_vector_type(8)));
typedef short short4v __attribute__((ext_vector_type(4)));
typedef float f32x4 __attribute__((ext_vector_type(4)));

#define BATCH 16
#define SEQ   4096
#define DIM   64
#define KVB   64              // base key chunk (frag-linear unit)
#define NCH   (SEQ / KVB)     // 64 chunks
#define NP2   32              // pass-2 iterations (128-key chunks)
#define NP1   16              // pass-1 iterations (256-key superchunks)
#define EL_CH 4096            // elems per 64-key chunk per tensor
#define EL_SC 8192            // elems per 128-key chunk per tensor
#define EL_P1 16384           // elems per 256-key pass-1 superchunk
#define EL_B  (NCH * EL_CH)   // elems per batch per tensor (262144)
#define PHS   264             // Ph row stride in halves (256 + 8 pad)

__device__ __forceinline__ short f2bf(float f) {
    unsigned u = __builtin_bit_cast(unsigned, f);
    u += 0x7FFF + ((u >> 16) & 1);          // round-to-nearest-even
    return (short)(u >> 16);
}
__device__ __forceinline__ float bf2f(short h) {
    return __builtin_bit_cast(float, (unsigned)((unsigned short)h) << 16);
}

__device__ __forceinline__ void gld16(const void* g, void* l) {
    __builtin_amdgcn_global_load_lds(
        (const __attribute__((address_space(1))) unsigned int*)g,
        (__attribute__((address_space(3))) unsigned int*)l, 16, 0, 0);
}

// ======== pre-kernel: K,V -> fp16 frag-linear (unchanged) ========
// K frag(ch,nf,kk,lane) = K[ch*64 + nf*16 + (lane&15)][kk*32 + (lane>>4)*8 + e]
// V frag(ch,nf,kk,lane) = V[ch*64 + kk*32 + (lane>>4)*8 + e][nf*16 + (lane&15)]
__global__ __launch_bounds__(256) void preconvert(
    const float* __restrict__ k, const float* __restrict__ v,
    _Float16* __restrict__ kh, _Float16* __restrict__ vh)
{
    int f = blockIdx.x * 256 + threadIdx.x;   // 0 .. 2*524288-1
    int lane = f & 63;
    int sub  = (f >> 6) & 7;                  // nf*2 + kk
    int ch   = (f >> 9) & 63;
    int bb   = (f >> 15) & 15;
    int isV  = f >> 19;
    int nf = sub >> 1, kk = sub & 1;
    size_t fo = (size_t)(f & ((1 << 19) - 1)) * 8;

    if (!isV) {
        int key = ch * 64 + nf * 16 + (lane & 15);
        int d0  = kk * 32 + (lane >> 4) * 8;
        const float* src = k + (((size_t)bb * SEQ + key) * DIM + d0);
        half8 h8;
        #pragma unroll
        for (int e = 0; e < 8; ++e) h8[e] = (_Float16)src[e];
        *(half8*)(kh + fo) = h8;
    } else {
        int kr0 = kk * 32 + (lane >> 4) * 8;
        int d   = nf * 16 + (lane & 15);
        const float* src = v + (((size_t)bb * SEQ + ch * 64 + kr0) * DIM + d);
        half8 h8;
        #pragma unroll
        for (int e = 0; e < 8; ++e) h8[e] = (_Float16)src[e * DIM];
        *(half8*)(vh + fo) = h8;
    }
}

// ============================== main kernel ==============================
// r15 skeleton + (a) pass-1 on 256-key superchunks (16 iters), (b) P buffered
// for 256 keys/row so att stores are 1KB-contiguous per instruction.
__global__ __launch_bounds__(512, 2) void attn_main(
    const float* __restrict__ q, const _Float16* __restrict__ kh,
    const _Float16* __restrict__ vh, float* __restrict__ ctx,
    float* __restrict__ att)
{
    // manually carved pool: 66560 halves = 130 KB
    // [0, 8192)      K buf0      [8192, 16384)  K buf1
    // [16384, 24576) V buf0      [24576, 32768) V buf1
    // [32768, 66560) Ph[8][16][264]
    // pass 1 aliases [0, 16384) and [16384, 32768) as 2 x 32KB superchunk bufs
    __shared__ __align__(16) _Float16 POOL[66560];

    int id = blockIdx.x;                  // grid = 512
    int bb = (id & 7) + 8 * (id >> 8);    // XCD-swizzled batch
    int qt = (id >> 3) & 31;              // 32 q-tiles of 128 rows

    int tid = threadIdx.x;
    int w = tid >> 6, lane = tid & 63, li = lane & 15, h4 = lane >> 4;

    _Float16* Ph = POOL + 32768 + w * (16 * PHS);   // this wave's P[16][PHS]

    // ---- Q B-fragments (fp16): this thread's q-row is qrow (q = li) ----
    int qrow = qt * 128 + w * 16 + li;
    const float* qp = q + ((size_t)bb * SEQ + qrow) * DIM;
    half8 aq[2];
    #pragma unroll
    for (int kk = 0; kk < 2; ++kk)
        #pragma unroll
        for (int e = 0; e < 8; ++e)
            aq[kk][e] = (_Float16)qp[kk * 32 + h4 * 8 + e];

    const _Float16* khb = kh + (size_t)bb * EL_B;
    const _Float16* vvb = vh + (size_t)bb * EL_B;

    // swapped QK^T from a frag-linear LDS base: s[nf][r]=S[q=li][16nf+4h4+r]
    auto qkt = [&](const _Float16* base, f32x4* s) {
        const half8* k8 = (const half8*)base;
        #pragma unroll
        for (int kk = 0; kk < 2; ++kk)
            #pragma unroll
            for (int nf = 0; nf < 4; ++nf)
                s[nf] = __builtin_amdgcn_mfma_f32_16x16x32_f16(
                    k8[(nf * 2 + kk) * 64 + lane], aq[kk], s[nf], 0, 0, 0);
    };

    // ========== pass 1: l = sum exp(s), 256-key superchunks (16 iters) =====
    float ll = 0.f;

    auto stage_p1 = [&](int buf, int sc) {        // 32 KB superchunk, 4 gld16
        const _Float16* g = khb + (size_t)sc * EL_P1 + tid * 8;
        _Float16* d = POOL + buf * EL_P1;
        gld16(g,         d + w * 512);
        gld16(g + 4096,  d + 4096  + w * 512);
        gld16(g + 8192,  d + 8192  + w * 512);
        gld16(g + 12288, d + 12288 + w * 512);
    };

    stage_p1(0, 0);
    for (int sc = 0; sc < NP1; ++sc) {
        int buf = sc & 1;
        if (sc + 1 < NP1) {
            stage_p1(buf ^ 1, sc + 1);
            asm volatile("s_waitcnt vmcnt(4)" ::: "memory");
        } else {
            asm volatile("s_waitcnt vmcnt(0)" ::: "memory");
        }
        __builtin_amdgcn_s_barrier();
        asm volatile("" ::: "memory");

        #pragma unroll
        for (int c4 = 0; c4 < 4; ++c4) {
            f32x4 s[4];
            #pragma unroll
            for (int nf = 0; nf < 4; ++nf) s[nf] = (f32x4){0.f, 0.f, 0.f, 0.f};
            qkt(POOL + buf * EL_P1 + c4 * EL_CH, s);
            float a = 0.f;
            #pragma unroll
            for (int nf = 0; nf < 4; ++nf)
                #pragma unroll
                for (int r = 0; r < 4; ++r)
                    a += __expf(s[nf][r]);
            ll += a;
        }

        asm volatile("" ::: "memory");
        __builtin_amdgcn_s_barrier();
    }

    // reduce over the 4 lanes sharing this q-row (h4 group), invert
    ll += __shfl_xor(ll, 16);
    ll += __shfl_xor(ll, 32);
    float rl = 1.0f / ll;

    // ========== pass 2: 128-key chunks; stores every 2 chunks, 1KB runs ====
    f32x4 acc[4];
    #pragma unroll
    for (int nf = 0; nf < 4; ++nf) acc[nf] = (f32x4){0.f, 0.f, 0.f, 0.f};

    float* attb = att + ((size_t)bb * SEQ + (size_t)qt * 128 + w * 16) * SEQ;

    auto stage_k2 = [&](int buf, int sc) {        // 2 gld16 (16 KB K chunk)
        const _Float16* g = khb + (size_t)sc * EL_SC + tid * 8;
        _Float16* d = POOL + buf * EL_SC;
        gld16(g,        d + w * 512);
        gld16(g + 4096, d + 4096 + w * 512);
    };
    auto stage_v2 = [&](int buf, int sc) {        // 2 gld16 (16 KB V chunk)
        const _Float16* g = vvb + (size_t)sc * EL_SC + tid * 8;
        _Float16* d = POOL + 16384 + buf * EL_SC;
        gld16(g,        d + w * 512);
        gld16(g + 4096, d + 4096 + w * 512);
    };
    // store pair p: att keys [p*256, p*256+256) for this wave's 16 rows,
    // one instruction per row = 64 lanes x 16B = 1KB contiguous
    auto store_pair = [&](int p) {
        #pragma unroll
        for (int row = 0; row < 16; ++row) {
            half4 ph = *(const half4*)&Ph[row * PHS + lane * 4];
            f32x4 pv = { (float)ph[0], (float)ph[1], (float)ph[2], (float)ph[3] };
            __builtin_nontemporal_store(
                pv, (f32x4*)(attb + (size_t)row * SEQ + p * 256 + lane * 4));
        }
    };

    stage_k2(0, 0); stage_v2(0, 0);
    for (int sc = 0; sc < NP2; ++sc) {
        int buf = sc & 1;
        if (sc + 1 < NP2) {
            stage_k2(buf ^ 1, sc + 1);
            stage_v2(buf ^ 1, sc + 1);
        }
        // stores for completed pair BEFORE compute overwrites Ph slot 0
        if (sc >= 2 && (sc & 1) == 0) store_pair(sc / 2 - 1);

        if (sc < 2)            asm volatile("s_waitcnt vmcnt(4)"  ::: "memory");
        else if (sc + 1 < NP2) asm volatile("s_waitcnt vmcnt(20)" ::: "memory");
        else                   asm volatile("s_waitcnt vmcnt(16)" ::: "memory");
        __builtin_amdgcn_s_barrier();
        asm volatile("" ::: "memory");

        // QK^T for both 64-key halves of this 128-key chunk
        const _Float16* kc = POOL + buf * EL_SC;
        f32x4 sA[4], sB[4];
        #pragma unroll
        for (int nf = 0; nf < 4; ++nf) {
            sA[nf] = (f32x4){0.f, 0.f, 0.f, 0.f};
            sB[nf] = (f32x4){0.f, 0.f, 0.f, 0.f};
        }
        qkt(kc,         sA);
        qkt(kc + EL_CH, sB);

        // p -> Ph[q=li][slot + key]: ds_write_b64 per 4-key group
        int slot = (sc & 1) * 128;
        #pragma unroll
        for (int nf = 0; nf < 4; ++nf) {
            half4 pa, pb;
            #pragma unroll
            for (int r = 0; r < 4; ++r) {
                pa[r] = (_Float16)(__expf(sA[nf][r]) * rl);
                pb[r] = (_Float16)(__expf(sB[nf][r]) * rl);
            }
            *(half4*)&Ph[li * PHS + slot + nf * 16 + h4 * 4]      = pa;
            *(half4*)&Ph[li * PHS + slot + 64 + nf * 16 + h4 * 4] = pb;
        }

        // PV over 128 keys: 16 MFMA
        const half8* v8 = (const half8*)(POOL + 16384 + buf * EL_SC);
        #pragma unroll
        for (int kk = 0; kk < 4; ++kk) {
            half8 pa = *(const half8*)&Ph[li * PHS + slot + kk * 32 + h4 * 8];
            #pragma unroll
            for (int nf = 0; nf < 4; ++nf)
                acc[nf] = __builtin_amdgcn_mfma_f32_16x16x32_f16(
                    pa, v8[(kk >> 1) * 512 + (nf * 2 + (kk & 1)) * 64 + lane],
                    acc[nf], 0, 0, 0);
        }

        asm volatile("" ::: "memory");
        __builtin_amdgcn_s_barrier();
    }
    store_pair(NP2 / 2 - 1);

    float* ctxb = ctx + ((size_t)bb * SEQ + (size_t)qt * 128 + w * 16) * DIM;
    #pragma unroll
    for (int nf = 0; nf < 4; ++nf)
        #pragma unroll
        for (int r = 0; r < 4; ++r)
            __builtin_nontemporal_store(
                acc[nf][r], &ctxb[(size_t)(4 * h4 + r) * DIM + nf * 16 + li]);
}

// ===================== fallback (round-2 kernel, proven) =====================
__global__ __launch_bounds__(256) void attn_fallback(
    const float* __restrict__ q, const float* __restrict__ k,
    const float* __restrict__ v, float* __restrict__ ctx,
    float* __restrict__ att)
{
    __shared__ short K_hi[KVB][72];
    __shared__ short K_lo[KVB][72];
    __shared__ short V_lds[DIM][72];
    __shared__ short P_lds[4][16][72];

    int id = blockIdx.x;
    int bb = (id & 7) + 8 * (id >> 9);
    int qt = (id >> 3) & 63;
    int tid = threadIdx.x;
    int w = tid >> 6, lane = tid & 63, li = lane & 15, h4 = lane >> 4;

    int qrow = qt * 64 + w * 16 + li;
    const float* qp = q + ((size_t)bb * SEQ + qrow) * DIM;
    short8 aq[2], aql[2];
    #pragma unroll
    for (int kk = 0; kk < 2; ++kk)
        #pragma unroll
        for (int e = 0; e < 8; ++e) {
            float x = qp[kk * 32 + h4 * 8 + e];
            short h = f2bf(x);
            aq[kk][e] = h; aql[kk][e] = f2bf(x - bf2f(h));
        }

    float m[4], l[4];
    #pragma unroll
    for (int r = 0; r < 4; ++r) { m[r] = -3.0e38f; l[r] = 0.0f; }
    const float* kbase = k + (size_t)bb * SEQ * DIM;
    const float* vbase = v + (size_t)bb * SEQ * DIM;

    for (int ch = 0; ch < NCH; ++ch) {
        __syncthreads();
        const float4* kc = (const float4*)(kbase + (size_t)ch * KVB * DIM);
        #pragma unroll
        for (int j = 0; j < 4; ++j) {
            int f4 = j * 256 + tid; int key = f4 >> 4, d4 = f4 & 15;
            float4 val = kc[f4];
            short4v h4v, l4v;
            h4v[0]=f2bf(val.x); l4v[0]=f2bf(val.x-bf2f(h4v[0]));
            h4v[1]=f2bf(val.y); l4v[1]=f2bf(val.y-bf2f(h4v[1]));
            h4v[2]=f2bf(val.z); l4v[2]=f2bf(val.z-bf2f(h4v[2]));
            h4v[3]=f2bf(val.w); l4v[3]=f2bf(val.w-bf2f(h4v[3]));
            *(short4v*)&K_hi[key][d4*4] = h4v;
            *(short4v*)&K_lo[key][d4*4] = l4v;
        }
        __syncthreads();
        f32x4 s[4];
        #pragma unroll
        for (int nf = 0; nf < 4; ++nf) s[nf] = (f32x4){0.f,0.f,0.f,0.f};
        #pragma unroll
        for (int kk = 0; kk < 2; ++kk)
            #pragma unroll
            for (int nf = 0; nf < 4; ++nf) {
                short8 kbv = *(const short8*)&K_hi[nf*16+li][kk*32+h4*8];
                short8 klv = *(const short8*)&K_lo[nf*16+li][kk*32+h4*8];
                s[nf] = __builtin_amdgcn_mfma_f32_16x16x32_bf16(aq[kk],  kbv, s[nf],0,0,0);
                s[nf] = __builtin_amdgcn_mfma_f32_16x16x32_bf16(aq[kk],  klv, s[nf],0,0,0);
                s[nf] = __builtin_amdgcn_mfma_f32_16x16x32_bf16(aql[kk], kbv, s[nf],0,0,0);
            }
        #pragma unroll
        for (int r = 0; r < 4; ++r) {
            float cmax = fmaxf(fmaxf(s[0][r],s[1][r]), fmaxf(s[2][r],s[3][r]));
            #pragma unroll
            for (int off = 1; off < 16; off <<= 1) cmax = fmaxf(cmax, __shfl_xor(cmax, off));
            float mnew = fmaxf(m[r], cmax);
            float cs = __expf(s[0][r]-mnew)+__expf(s[1][r]-mnew)+__expf(s[2][r]-mnew)+__expf(s[3][r]-mnew);
            #pragma unroll
            for (int off = 1; off < 16; off <<= 1) cs += __shfl_xor(cs, off);
            l[r] = l[r]*__expf(m[r]-mnew) + cs; m[r] = mnew;
        }
    }
    float rl[4];
    #pragma unroll
    for (int r = 0; r < 4; ++r) rl[r] = 1.0f / l[r];

    f32x4 acc[4];
    #pragma unroll
    for (int nf = 0; nf < 4; ++nf) acc[nf] = (f32x4){0.f,0.f,0.f,0.f};
    float* attb = att + ((size_t)bb * SEQ + (size_t)qt * 64 + w * 16) * SEQ;

    for (int ch = 0; ch < NCH; ++ch) {
        __syncthreads();
        const float4* kc = (const float4*)(kbase + (size_t)ch * KVB * DIM);
        #pragma unroll
        for (int j = 0; j < 4; ++j) {
            int f4 = j * 256 + tid; int key = f4 >> 4, d4 = f4 & 15;
            float4 val = kc[f4];
            short4v h4v, l4v;
            h4v[0]=f2bf(val.x); l4v[0]=f2bf(val.x-bf2f(h4v[0]));
            h4v[1]=f2bf(val.y); l4v[1]=f2bf(val.y-bf2f(h4v[1]));
            h4v[2]=f2bf(val.z); l4v[2]=f2bf(val.z-bf2f(h4v[2]));
            h4v[3]=f2bf(val.w); l4v[3]=f2bf(val.w-bf2f(h4v[3]));
            *(short4v*)&K_hi[key][d4*4] = h4v;
            *(short4v*)&K_lo[key][d4*4] = l4v;
        }
        {
            int key = tid & 63, dblk = (tid >> 6) * 16;
            const float* vc = vbase + ((size_t)ch * KVB + key) * DIM + dblk;
            #pragma unroll
            for (int j = 0; j < 4; ++j) {
                float4 val = *(const float4*)(vc + j * 4);
                V_lds[dblk+j*4+0][key]=f2bf(val.x); V_lds[dblk+j*4+1][key]=f2bf(val.y);
                V_lds[dblk+j*4+2][key]=f2bf(val.z); V_lds[dblk+j*4+3][key]=f2bf(val.w);
            }
        }
        __syncthreads();
        f32x4 s[4];
        #pragma unroll
        for (int nf = 0; nf < 4; ++nf) s[nf] = (f32x4){0.f,0.f,0.f,0.f};
        #pragma unroll
        for (int kk = 0; kk < 2; ++kk)
            #pragma unroll
            for (int nf = 0; nf < 4; ++nf) {
                short8 kbv = *(const short8*)&K_hi[nf*16+li][kk*32+h4*8];
                short8 klv = *(const short8*)&K_lo[nf*16+li][kk*32+h4*8];
                s[nf] = __builtin_amdgcn_mfma_f32_16x16x32_bf16(aq[kk],  kbv, s[nf],0,0,0);
                s[nf] = __builtin_amdgcn_mfma_f32_16x16x32_bf16(aq[kk],  klv, s[nf],0,0,0);
                s[nf] = __builtin_amdgcn_mfma_f32_16x16x32_bf16(aql[kk], kbv, s[nf],0,0,0);
            }
        #pragma unroll
        for (int nf = 0; nf < 4; ++nf)
            #pragma unroll
            for (int r = 0; r < 4; ++r) {
                float p = __expf(s[nf][r] - m[r]) * rl[r];
                __builtin_nontemporal_store(p, &attb[(size_t)(4*h4+r)*SEQ + ch*KVB + nf*16 + li]);
                P_lds[w][4*h4+r][nf*16+li] = f2bf(p);
            }
        #pragma unroll
        for (int kk = 0; kk < 2; ++kk) {
            short8 pa = *(const short8*)&P_lds[w][li][kk*32+h4*8];
            #pragma unroll
            for (int nf = 0; nf < 4; ++nf) {
                short8 vbv = *(const short8*)&V_lds[nf*16+li][kk*32+h4*8];
                acc[nf] = __builtin_amdgcn_mfma_f32_16x16x32_bf16(pa, vbv, acc[nf],0,0,0);
            }
        }
    }
    float* ctxb = ctx + ((size_t)bb * SEQ + (size_t)qt * 64 + w * 16) * DIM;
    #pragma unroll
    for (int nf = 0; nf < 4; ++nf)
        #pragma unroll
        for (int r = 0; r < 4; ++r)
            __builtin_nontemporal_store(acc[nf][r], &ctxb[(size_t)(4*h4+r)*DIM + nf*16 + li]);
}

extern "C" void kernel_launch(void* const* d_in, const int* in_sizes, int n_in,
                              void* d_out, int out_size, void* d_ws, size_t ws_size,
                              hipStream_t stream) {
    const float* q = (const float*)d_in[0];
    const float* k = (const float*)d_in[1];
    const float* v = (const float*)d_in[2];
    float* ctx = (float*)d_out;
    float* att = (float*)d_out + (size_t)BATCH * SEQ * DIM;

    const size_t t_el = (size_t)BATCH * EL_B;              // 4,194,304
    const size_t need = 2 * t_el * 2;                      // 16.8 MB

    if (ws_size >= need) {
        _Float16* kh = (_Float16*)d_ws;
        _Float16* vh = kh + t_el;
        preconvert<<<4096, 256, 0, stream>>>(k, v, kh, vh);
        attn_main<<<512, 512, 0, stream>>>(q, kh, vh, ctx, att);
    } else {
        attn_fallback<<<BATCH * (SEQ / 64), 256, 0, stream>>>(q, k, v, ctx, att);
    }
}

// Round 17
// 260.083 us; speedup vs baseline: 1.4723x; 1.0066x over previous
//
#include <hip/hip_runtime.h>
#include <hip/hip_bf16.h>

typedef _Float16 half8 __attribute__((ext_vector_type(8)));
typedef _Float16 half4 __attribute__((ext_vector_type(4)));
typedef short short8 __attribute__((ext_vector_type(8)));
typedef short short4v __attribute__((ext_vector_type(4)));
typedef float f32x4 __attribute__((ext_vector_type(4)));

#define BATCH 16
#define SEQ   4096
#define DIM   64
#define KVB   64              // base key chunk (frag-linear unit)
#define NCH   (SEQ / KVB)     // 64 chunks
#define NP2   32              // pass-2 iterations (128-key chunks)
#define NP1   8               // pass-1 iterations (512-key superchunks)
#define EL_CH 4096            // elems per 64-key chunk per tensor
#define EL_SC 8192            // elems per 128-key chunk per tensor
#define EL_P1 32768           // elems per 512-key pass-1 superchunk
#define EL_B  (NCH * EL_CH)   // elems per batch per tensor (262144)
#define PHS   264             // Ph row stride in halves (256 + 8 pad)

__device__ __forceinline__ short f2bf(float f) {
    unsigned u = __builtin_bit_cast(unsigned, f);
    u += 0x7FFF + ((u >> 16) & 1);          // round-to-nearest-even
    return (short)(u >> 16);
}
__device__ __forceinline__ float bf2f(short h) {
    return __builtin_bit_cast(float, (unsigned)((unsigned short)h) << 16);
}

__device__ __forceinline__ void gld16(const void* g, void* l) {
    __builtin_amdgcn_global_load_lds(
        (const __attribute__((address_space(1))) unsigned int*)g,
        (__attribute__((address_space(3))) unsigned int*)l, 16, 0, 0);
}

// ======== pre-kernel: K,V -> fp16 frag-linear (unchanged) ========
// K frag(ch,nf,kk,lane) = K[ch*64 + nf*16 + (lane&15)][kk*32 + (lane>>4)*8 + e]
// V frag(ch,nf,kk,lane) = V[ch*64 + kk*32 + (lane>>4)*8 + e][nf*16 + (lane&15)]
__global__ __launch_bounds__(256) void preconvert(
    const float* __restrict__ k, const float* __restrict__ v,
    _Float16* __restrict__ kh, _Float16* __restrict__ vh)
{
    int f = blockIdx.x * 256 + threadIdx.x;   // 0 .. 2*524288-1
    int lane = f & 63;
    int sub  = (f >> 6) & 7;                  // nf*2 + kk
    int ch   = (f >> 9) & 63;
    int bb   = (f >> 15) & 15;
    int isV  = f >> 19;
    int nf = sub >> 1, kk = sub & 1;
    size_t fo = (size_t)(f & ((1 << 19) - 1)) * 8;

    if (!isV) {
        int key = ch * 64 + nf * 16 + (lane & 15);
        int d0  = kk * 32 + (lane >> 4) * 8;
        const float* src = k + (((size_t)bb * SEQ + key) * DIM + d0);
        half8 h8;
        #pragma unroll
        for (int e = 0; e < 8; ++e) h8[e] = (_Float16)src[e];
        *(half8*)(kh + fo) = h8;
    } else {
        int kr0 = kk * 32 + (lane >> 4) * 8;
        int d   = nf * 16 + (lane & 15);
        const float* src = v + (((size_t)bb * SEQ + ch * 64 + kr0) * DIM + d);
        half8 h8;
        #pragma unroll
        for (int e = 0; e < 8; ++e) h8[e] = (_Float16)src[e * DIM];
        *(half8*)(vh + fo) = h8;
    }
}

// ============================== main kernel ==============================
// r16 skeleton + (a) pass-1 on 512-key superchunks (8 iters, whole pool
// aliased as 2 x 64KB), (b) ctx stores transposed via LDS -> 1KB runs.
__global__ __launch_bounds__(512, 2) void attn_main(
    const float* __restrict__ q, const _Float16* __restrict__ kh,
    const _Float16* __restrict__ vh, float* __restrict__ ctx,
    float* __restrict__ att)
{
    // manually carved pool: 66560 halves = 130 KB
    // pass1: [0,32768) buf0, [32768,65536) buf1  (512-key K superchunks)
    // pass2: [0,8192) K b0, [8192,16384) K b1,
    //        [16384,24576) V b0, [24576,32768) V b1, [32768,66560) Ph
    // epilogue: Ph region reused as float scratch for ctx transpose
    __shared__ __align__(16) _Float16 POOL[66560];

    int id = blockIdx.x;                  // grid = 512
    int bb = (id & 7) + 8 * (id >> 8);    // XCD-swizzled batch
    int qt = (id >> 3) & 31;              // 32 q-tiles of 128 rows

    int tid = threadIdx.x;
    int w = tid >> 6, lane = tid & 63, li = lane & 15, h4 = lane >> 4;

    _Float16* Ph = POOL + 32768 + w * (16 * PHS);   // this wave's P[16][PHS]

    // ---- Q B-fragments (fp16): this thread's q-row is qrow (q = li) ----
    int qrow = qt * 128 + w * 16 + li;
    const float* qp = q + ((size_t)bb * SEQ + qrow) * DIM;
    half8 aq[2];
    #pragma unroll
    for (int kk = 0; kk < 2; ++kk)
        #pragma unroll
        for (int e = 0; e < 8; ++e)
            aq[kk][e] = (_Float16)qp[kk * 32 + h4 * 8 + e];

    const _Float16* khb = kh + (size_t)bb * EL_B;
    const _Float16* vvb = vh + (size_t)bb * EL_B;

    // swapped QK^T from a frag-linear LDS base: s[nf][r]=S[q=li][16nf+4h4+r]
    auto qkt = [&](const _Float16* base, f32x4* s) {
        const half8* k8 = (const half8*)base;
        #pragma unroll
        for (int kk = 0; kk < 2; ++kk)
            #pragma unroll
            for (int nf = 0; nf < 4; ++nf)
                s[nf] = __builtin_amdgcn_mfma_f32_16x16x32_f16(
                    k8[(nf * 2 + kk) * 64 + lane], aq[kk], s[nf], 0, 0, 0);
    };

    // ========== pass 1: l = sum exp(s), 512-key superchunks (8 iters) ======
    float ll = 0.f;

    auto stage_p1 = [&](int buf, int sc) {        // 64 KB superchunk, 8 gld16
        const _Float16* g = khb + (size_t)sc * EL_P1 + tid * 8;
        _Float16* d = POOL + buf * EL_P1;
        #pragma unroll
        for (int o = 0; o < 8; ++o)
            gld16(g + o * 4096, d + o * 4096 + w * 512);
    };

    stage_p1(0, 0);
    for (int sc = 0; sc < NP1; ++sc) {
        int buf = sc & 1;
        if (sc + 1 < NP1) {
            stage_p1(buf ^ 1, sc + 1);
            asm volatile("s_waitcnt vmcnt(8)" ::: "memory");
        } else {
            asm volatile("s_waitcnt vmcnt(0)" ::: "memory");
        }
        __builtin_amdgcn_s_barrier();
        asm volatile("" ::: "memory");

        #pragma unroll
        for (int c8 = 0; c8 < 8; ++c8) {
            f32x4 s[4];
            #pragma unroll
            for (int nf = 0; nf < 4; ++nf) s[nf] = (f32x4){0.f, 0.f, 0.f, 0.f};
            qkt(POOL + buf * EL_P1 + c8 * EL_CH, s);
            float a = 0.f;
            #pragma unroll
            for (int nf = 0; nf < 4; ++nf)
                #pragma unroll
                for (int r = 0; r < 4; ++r)
                    a += __expf(s[nf][r]);
            ll += a;
        }

        asm volatile("" ::: "memory");
        __builtin_amdgcn_s_barrier();
    }

    // reduce over the 4 lanes sharing this q-row (h4 group), invert
    ll += __shfl_xor(ll, 16);
    ll += __shfl_xor(ll, 32);
    float rl = 1.0f / ll;

    // ========== pass 2: 128-key chunks; stores every 2 chunks, 1KB runs ====
    f32x4 acc[4];
    #pragma unroll
    for (int nf = 0; nf < 4; ++nf) acc[nf] = (f32x4){0.f, 0.f, 0.f, 0.f};

    float* attb = att + ((size_t)bb * SEQ + (size_t)qt * 128 + w * 16) * SEQ;

    auto stage_k2 = [&](int buf, int sc) {        // 2 gld16 (16 KB K chunk)
        const _Float16* g = khb + (size_t)sc * EL_SC + tid * 8;
        _Float16* d = POOL + buf * EL_SC;
        gld16(g,        d + w * 512);
        gld16(g + 4096, d + 4096 + w * 512);
    };
    auto stage_v2 = [&](int buf, int sc) {        // 2 gld16 (16 KB V chunk)
        const _Float16* g = vvb + (size_t)sc * EL_SC + tid * 8;
        _Float16* d = POOL + 16384 + buf * EL_SC;
        gld16(g,        d + w * 512);
        gld16(g + 4096, d + 4096 + w * 512);
    };
    // store pair p: att keys [p*256, p*256+256) for this wave's 16 rows,
    // one instruction per row = 64 lanes x 16B = 1KB contiguous
    auto store_pair = [&](int p) {
        #pragma unroll
        for (int row = 0; row < 16; ++row) {
            half4 ph = *(const half4*)&Ph[row * PHS + lane * 4];
            f32x4 pv = { (float)ph[0], (float)ph[1], (float)ph[2], (float)ph[3] };
            __builtin_nontemporal_store(
                pv, (f32x4*)(attb + (size_t)row * SEQ + p * 256 + lane * 4));
        }
    };

    stage_k2(0, 0); stage_v2(0, 0);
    for (int sc = 0; sc < NP2; ++sc) {
        int buf = sc & 1;
        if (sc + 1 < NP2) {
            stage_k2(buf ^ 1, sc + 1);
            stage_v2(buf ^ 1, sc + 1);
        }
        // stores for completed pair BEFORE compute overwrites Ph slot 0
        if (sc >= 2 && (sc & 1) == 0) store_pair(sc / 2 - 1);

        if (sc < 2)            asm volatile("s_waitcnt vmcnt(4)"  ::: "memory");
        else if (sc + 1 < NP2) asm volatile("s_waitcnt vmcnt(20)" ::: "memory");
        else                   asm volatile("s_waitcnt vmcnt(16)" ::: "memory");
        __builtin_amdgcn_s_barrier();
        asm volatile("" ::: "memory");

        // QK^T for both 64-key halves of this 128-key chunk
        const _Float16* kc = POOL + buf * EL_SC;
        f32x4 sA[4], sB[4];
        #pragma unroll
        for (int nf = 0; nf < 4; ++nf) {
            sA[nf] = (f32x4){0.f, 0.f, 0.f, 0.f};
            sB[nf] = (f32x4){0.f, 0.f, 0.f, 0.f};
        }
        qkt(kc,         sA);
        qkt(kc + EL_CH, sB);

        // p -> Ph[q=li][slot + key]: ds_write_b64 per 4-key group
        int slot = (sc & 1) * 128;
        #pragma unroll
        for (int nf = 0; nf < 4; ++nf) {
            half4 pa, pb;
            #pragma unroll
            for (int r = 0; r < 4; ++r) {
                pa[r] = (_Float16)(__expf(sA[nf][r]) * rl);
                pb[r] = (_Float16)(__expf(sB[nf][r]) * rl);
            }
            *(half4*)&Ph[li * PHS + slot + nf * 16 + h4 * 4]      = pa;
            *(half4*)&Ph[li * PHS + slot + 64 + nf * 16 + h4 * 4] = pb;
        }

        // PV over 128 keys: 16 MFMA
        const half8* v8 = (const half8*)(POOL + 16384 + buf * EL_SC);
        #pragma unroll
        for (int kk = 0; kk < 4; ++kk) {
            half8 pa = *(const half8*)&Ph[li * PHS + slot + kk * 32 + h4 * 8];
            #pragma unroll
            for (int nf = 0; nf < 4; ++nf)
                acc[nf] = __builtin_amdgcn_mfma_f32_16x16x32_f16(
                    pa, v8[(kk >> 1) * 512 + (nf * 2 + (kk & 1)) * 64 + lane],
                    acc[nf], 0, 0, 0);
        }

        asm volatile("" ::: "memory");
        __builtin_amdgcn_s_barrier();
    }
    store_pair(NP2 / 2 - 1);

    // ---- ctx: transpose via LDS -> 1KB-contiguous NT stores ----
    __syncthreads();                       // Ph region reuse as float scratch
    float* Phf = (float*)(POOL + 32768) + w * (16 * 68);
    #pragma unroll
    for (int nf = 0; nf < 4; ++nf)
        #pragma unroll
        for (int r = 0; r < 4; ++r)
            Phf[(4 * h4 + r) * 68 + nf * 16 + li] = acc[nf][r];
    __syncthreads();
    float* ctxw = ctx + ((size_t)bb * SEQ + (size_t)qt * 128 + w * 16) * DIM;
    #pragma unroll
    for (int j = 0; j < 4; ++j) {
        int row = j * 4 + (lane >> 4);
        f32x4 cv = *(const f32x4*)&Phf[row * 68 + (lane & 15) * 4];
        __builtin_nontemporal_store(
            cv, (f32x4*)(ctxw + (size_t)row * DIM + (lane & 15) * 4));
    }
}

// ===================== fallback (round-2 kernel, proven) =====================
__global__ __launch_bounds__(256) void attn_fallback(
    const float* __restrict__ q, const float* __restrict__ k,
    const float* __restrict__ v, float* __restrict__ ctx,
    float* __restrict__ att)
{
    __shared__ short K_hi[KVB][72];
    __shared__ short K_lo[KVB][72];
    __shared__ short V_lds[DIM][72];
    __shared__ short P_lds[4][16][72];

    int id = blockIdx.x;
    int bb = (id & 7) + 8 * (id >> 9);
    int qt = (id >> 3) & 63;
    int tid = threadIdx.x;
    int w = tid >> 6, lane = tid & 63, li = lane & 15, h4 = lane >> 4;

    int qrow = qt * 64 + w * 16 + li;
    const float* qp = q + ((size_t)bb * SEQ + qrow) * DIM;
    short8 aq[2], aql[2];
    #pragma unroll
    for (int kk = 0; kk < 2; ++kk)
        #pragma unroll
        for (int e = 0; e < 8; ++e) {
            float x = qp[kk * 32 + h4 * 8 + e];
            short h = f2bf(x);
            aq[kk][e] = h; aql[kk][e] = f2bf(x - bf2f(h));
        }

    float m[4], l[4];
    #pragma unroll
    for (int r = 0; r < 4; ++r) { m[r] = -3.0e38f; l[r] = 0.0f; }
    const float* kbase = k + (size_t)bb * SEQ * DIM;
    const float* vbase = v + (size_t)bb * SEQ * DIM;

    for (int ch = 0; ch < NCH; ++ch) {
        __syncthreads();
        const float4* kc = (const float4*)(kbase + (size_t)ch * KVB * DIM);
        #pragma unroll
        for (int j = 0; j < 4; ++j) {
            int f4 = j * 256 + tid; int key = f4 >> 4, d4 = f4 & 15;
            float4 val = kc[f4];
            short4v h4v, l4v;
            h4v[0]=f2bf(val.x); l4v[0]=f2bf(val.x-bf2f(h4v[0]));
            h4v[1]=f2bf(val.y); l4v[1]=f2bf(val.y-bf2f(h4v[1]));
            h4v[2]=f2bf(val.z); l4v[2]=f2bf(val.z-bf2f(h4v[2]));
            h4v[3]=f2bf(val.w); l4v[3]=f2bf(val.w-bf2f(h4v[3]));
            *(short4v*)&K_hi[key][d4*4] = h4v;
            *(short4v*)&K_lo[key][d4*4] = l4v;
        }
        __syncthreads();
        f32x4 s[4];
        #pragma unroll
        for (int nf = 0; nf < 4; ++nf) s[nf] = (f32x4){0.f,0.f,0.f,0.f};
        #pragma unroll
        for (int kk = 0; kk < 2; ++kk)
            #pragma unroll
            for (int nf = 0; nf < 4; ++nf) {
                short8 kbv = *(const short8*)&K_hi[nf*16+li][kk*32+h4*8];
                short8 klv = *(const short8*)&K_lo[nf*16+li][kk*32+h4*8];
                s[nf] = __builtin_amdgcn_mfma_f32_16x16x32_bf16(aq[kk],  kbv, s[nf],0,0,0);
                s[nf] = __builtin_amdgcn_mfma_f32_16x16x32_bf16(aq[kk],  klv, s[nf],0,0,0);
                s[nf] = __builtin_amdgcn_mfma_f32_16x16x32_bf16(aql[kk], kbv, s[nf],0,0,0);
            }
        #pragma unroll
        for (int r = 0; r < 4; ++r) {
            float cmax = fmaxf(fmaxf(s[0][r],s[1][r]), fmaxf(s[2][r],s[3][r]));
            #pragma unroll
            for (int off = 1; off < 16; off <<= 1) cmax = fmaxf(cmax, __shfl_xor(cmax, off));
            float mnew = fmaxf(m[r], cmax);
            float cs = __expf(s[0][r]-mnew)+__expf(s[1][r]-mnew)+__expf(s[2][r]-mnew)+__expf(s[3][r]-mnew);
            #pragma unroll
            for (int off = 1; off < 16; off <<= 1) cs += __shfl_xor(cs, off);
            l[r] = l[r]*__expf(m[r]-mnew) + cs; m[r] = mnew;
        }
    }
    float rl[4];
    #pragma unroll
    for (int r = 0; r < 4; ++r) rl[r] = 1.0f / l[r];

    f32x4 acc[4];
    #pragma unroll
    for (int nf = 0; nf < 4; ++nf) acc[nf] = (f32x4){0.f,0.f,0.f,0.f};
    float* attb = att + ((size_t)bb * SEQ + (size_t)qt * 64 + w * 16) * SEQ;

    for (int ch = 0; ch < NCH; ++ch) {
        __syncthreads();
        const float4* kc = (const float4*)(kbase + (size_t)ch * KVB * DIM);
        #pragma unroll
        for (int j = 0; j < 4; ++j) {
            int f4 = j * 256 + tid; int key = f4 >> 4, d4 = f4 & 15;
            float4 val = kc[f4];
            short4v h4v, l4v;
            h4v[0]=f2bf(val.x); l4v[0]=f2bf(val.x-bf2f(h4v[0]));
            h4v[1]=f2bf(val.y); l4v[1]=f2bf(val.y-bf2f(h4v[1]));
            h4v[2]=f2bf(val.z); l4v[2]=f2bf(val.z-bf2f(h4v[2]));
            h4v[3]=f2bf(val.w); l4v[3]=f2bf(val.w-bf2f(h4v[3]));
            *(short4v*)&K_hi[key][d4*4] = h4v;
            *(short4v*)&K_lo[key][d4*4] = l4v;
        }
        {
            int key = tid & 63, dblk = (tid >> 6) * 16;
            const float* vc = vbase + ((size_t)ch * KVB + key) * DIM + dblk;
            #pragma unroll
            for (int j = 0; j < 4; ++j) {
                float4 val = *(const float4*)(vc + j * 4);
                V_lds[dblk+j*4+0][key]=f2bf(val.x); V_lds[dblk+j*4+1][key]=f2bf(val.y);
                V_lds[dblk+j*4+2][key]=f2bf(val.z); V_lds[dblk+j*4+3][key]=f2bf(val.w);
            }
        }
        __syncthreads();
        f32x4 s[4];
        #pragma unroll
        for (int nf = 0; nf < 4; ++nf) s[nf] = (f32x4){0.f,0.f,0.f,0.f};
        #pragma unroll
        for (int kk = 0; kk < 2; ++kk)
            #pragma unroll
            for (int nf = 0; nf < 4; ++nf) {
                short8 kbv = *(const short8*)&K_hi[nf*16+li][kk*32+h4*8];
                short8 klv = *(const short8*)&K_lo[nf*16+li][kk*32+h4*8];
                s[nf] = __builtin_amdgcn_mfma_f32_16x16x32_bf16(aq[kk],  kbv, s[nf],0,0,0);
                s[nf] = __builtin_amdgcn_mfma_f32_16x16x32_bf16(aq[kk],  klv, s[nf],0,0,0);
                s[nf] = __builtin_amdgcn_mfma_f32_16x16x32_bf16(aql[kk], kbv, s[nf],0,0,0);
            }
        #pragma unroll
        for (int nf = 0; nf < 4; ++nf)
            #pragma unroll
            for (int r = 0; r < 4; ++r) {
                float p = __expf(s[nf][r] - m[r]) * rl[r];
                __builtin_nontemporal_store(p, &attb[(size_t)(4*h4+r)*SEQ + ch*KVB + nf*16 + li]);
                P_lds[w][4*h4+r][nf*16+li] = f2bf(p);
            }
        #pragma unroll
        for (int kk = 0; kk < 2; ++kk) {
            short8 pa = *(const short8*)&P_lds[w][li][kk*32+h4*8];
            #pragma unroll
            for (int nf = 0; nf < 4; ++nf) {
                short8 vbv = *(const short8*)&V_lds[nf*16+li][kk*32+h4*8];
                acc[nf] = __builtin_amdgcn_mfma_f32_16x16x32_bf16(pa, vbv, acc[nf],0,0,0);
            }
        }
    }
    float* ctxb = ctx + ((size_t)bb * SEQ + (size_t)qt * 64 + w * 16) * DIM;
    #pragma unroll
    for (int nf = 0; nf < 4; ++nf)
        #pragma unroll
        for (int r = 0; r < 4; ++r)
            __builtin_nontemporal_store(acc[nf][r], &ctxb[(size_t)(4*h4+r)*DIM + nf*16 + li]);
}

extern "C" void kernel_launch(void* const* d_in, const int* in_sizes, int n_in,
                              void* d_out, int out_size, void* d_ws, size_t ws_size,
                              hipStream_t stream) {
    const float* q = (const float*)d_in[0];
    const float* k = (const float*)d_in[1];
    const float* v = (const float*)d_in[2];
    float* ctx = (float*)d_out;
    float* att = (float*)d_out + (size_t)BATCH * SEQ * DIM;

    const size_t t_el = (size_t)BATCH * EL_B;              // 4,194,304
    const size_t need = 2 * t_el * 2;                      // 16.8 MB

    if (ws_size >= need) {
        _Float16* kh = (_Float16*)d_ws;
        _Float16* vh = kh + t_el;
        preconvert<<<4096, 256, 0, stream>>>(k, v, kh, vh);
        attn_main<<<512, 512, 0, stream>>>(q, kh, vh, ctx, att);
    } else {
        attn_fallback<<<BATCH * (SEQ / 64), 256, 0, stream>>>(q, k, v, ctx, att);
    }
}

// Round 18
// 248.985 us; speedup vs baseline: 1.5379x; 1.0446x over previous
//
#include <hip/hip_runtime.h>
#include <hip/hip_bf16.h>

typedef _Float16 half8 __attribute__((ext_vector_type(8)));
typedef _Float16 half4 __attribute__((ext_vector_type(4)));
typedef short short8 __attribute__((ext_vector_type(8)));
typedef short short4v __attribute__((ext_vector_type(4)));
typedef float f32x4 __attribute__((ext_vector_type(4)));

#define BATCH 16
#define SEQ   4096
#define DIM   64
#define KVB   64              // base key chunk (frag-linear unit)
#define NCH   (SEQ / KVB)     // 64 chunks
#define NP2   32              // pass-2 iterations (128-key chunks)
#define NP1   8               // pass-1 iterations (512-key superchunks)
#define EL_CH 4096            // elems per 64-key chunk per tensor
#define EL_SC 8192            // elems per 128-key chunk per tensor
#define EL_P1 32768           // elems per 512-key pass-1 superchunk
#define EL_B  (NCH * EL_CH)   // elems per batch per tensor (262144)
#define PHS   136             // Ph row stride in halves (128 + 8 pad)

__device__ __forceinline__ short f2bf(float f) {
    unsigned u = __builtin_bit_cast(unsigned, f);
    u += 0x7FFF + ((u >> 16) & 1);          // round-to-nearest-even
    return (short)(u >> 16);
}
__device__ __forceinline__ float bf2f(short h) {
    return __builtin_bit_cast(float, (unsigned)((unsigned short)h) << 16);
}

__device__ __forceinline__ void gld16(const void* g, void* l) {
    __builtin_amdgcn_global_load_lds(
        (const __attribute__((address_space(1))) unsigned int*)g,
        (__attribute__((address_space(3))) unsigned int*)l, 16, 0, 0);
}

// ======== pre-kernel: K,V -> fp16 frag-linear (unchanged) ========
// K frag(ch,nf,kk,lane) = K[ch*64 + nf*16 + (lane&15)][kk*32 + (lane>>4)*8 + e]
// V frag(ch,nf,kk,lane) = V[ch*64 + kk*32 + (lane>>4)*8 + e][nf*16 + (lane&15)]
__global__ __launch_bounds__(256) void preconvert(
    const float* __restrict__ k, const float* __restrict__ v,
    _Float16* __restrict__ kh, _Float16* __restrict__ vh)
{
    int f = blockIdx.x * 256 + threadIdx.x;   // 0 .. 2*524288-1
    int lane = f & 63;
    int sub  = (f >> 6) & 7;                  // nf*2 + kk
    int ch   = (f >> 9) & 63;
    int bb   = (f >> 15) & 15;
    int isV  = f >> 19;
    int nf = sub >> 1, kk = sub & 1;
    size_t fo = (size_t)(f & ((1 << 19) - 1)) * 8;

    if (!isV) {
        int key = ch * 64 + nf * 16 + (lane & 15);
        int d0  = kk * 32 + (lane >> 4) * 8;
        const float* src = k + (((size_t)bb * SEQ + key) * DIM + d0);
        half8 h8;
        #pragma unroll
        for (int e = 0; e < 8; ++e) h8[e] = (_Float16)src[e];
        *(half8*)(kh + fo) = h8;
    } else {
        int kr0 = kk * 32 + (lane >> 4) * 8;
        int d   = nf * 16 + (lane & 15);
        const float* src = v + (((size_t)bb * SEQ + ch * 64 + kr0) * DIM + d);
        half8 h8;
        #pragma unroll
        for (int e = 0; e < 8; ++e) h8[e] = (_Float16)src[e * DIM];
        *(half8*)(vh + fo) = h8;
    }
}

// ============================== main kernel ==============================
// ONE block per CU (grid 256): each block owns 256 q-rows = 2 tiles of 128,
// processed sequentially per K/V chunk. Halves the per-iteration lockstep
// overhead and the K/V re-read traffic; att stores are 512B runs.
__global__ __launch_bounds__(512, 2) void attn_main(
    const float* __restrict__ q, const _Float16* __restrict__ kh,
    const _Float16* __restrict__ vh, float* __restrict__ ctx,
    float* __restrict__ att)
{
    // pool: 65536 halves = 128 KB
    // pass1: [0,32768) buf0, [32768,65536) buf1  (512-key K superchunks)
    // pass2: [0,8192) K b0, [8192,16384) K b1,
    //        [16384,24576) V b0, [24576,32768) V b1,
    //        [32768,50176) Ph[8][16][136]
    // epilogue: Ph region reused as float scratch for ctx transpose
    __shared__ __align__(16) _Float16 POOL[65536];

    int id = blockIdx.x;                  // grid = 256
    int bb = (id & 7) + 8 * (id >> 7);    // XCD-swizzled batch
    int qt = (id >> 3) & 15;              // 16 q-supertiles of 256 rows

    int tid = threadIdx.x;
    int w = tid >> 6, lane = tid & 63, li = lane & 15, h4 = lane >> 4;

    _Float16* Ph = POOL + 32768 + w * (16 * PHS);   // this wave's P[16][PHS]

    // ---- Q B-fragments (fp16) for BOTH tiles: q-rows base+li, base+128+li --
    int rowA = qt * 256 + w * 16 + li;
    const float* qpA = q + ((size_t)bb * SEQ + rowA) * DIM;
    const float* qpB = qpA + (size_t)128 * DIM;
    half8 aqA[2], aqB[2];
    #pragma unroll
    for (int kk = 0; kk < 2; ++kk)
        #pragma unroll
        for (int e = 0; e < 8; ++e) {
            aqA[kk][e] = (_Float16)qpA[kk * 32 + h4 * 8 + e];
            aqB[kk][e] = (_Float16)qpB[kk * 32 + h4 * 8 + e];
        }

    const _Float16* khb = kh + (size_t)bb * EL_B;
    const _Float16* vvb = vh + (size_t)bb * EL_B;

    // swapped QK^T from a frag-linear LDS base: s[nf][r]=S[q=li][16nf+4h4+r]
    auto qkt = [&](const _Float16* base, const half8* aq, f32x4* s) {
        const half8* k8 = (const half8*)base;
        #pragma unroll
        for (int kk = 0; kk < 2; ++kk)
            #pragma unroll
            for (int nf = 0; nf < 4; ++nf)
                s[nf] = __builtin_amdgcn_mfma_f32_16x16x32_f16(
                    k8[(nf * 2 + kk) * 64 + lane], aq[kk], s[nf], 0, 0, 0);
    };

    // ========== pass 1: l = sum exp(s), 512-key superchunks (8 iters) ======
    float llA = 0.f, llB = 0.f;

    auto stage_p1 = [&](int buf, int sc) {        // 64 KB superchunk, 8 gld16
        const _Float16* g = khb + (size_t)sc * EL_P1 + tid * 8;
        _Float16* d = POOL + buf * EL_P1;
        #pragma unroll
        for (int o = 0; o < 8; ++o)
            gld16(g + o * 4096, d + o * 4096 + w * 512);
    };

    stage_p1(0, 0);
    for (int sc = 0; sc < NP1; ++sc) {
        int buf = sc & 1;
        if (sc + 1 < NP1) {
            stage_p1(buf ^ 1, sc + 1);
            asm volatile("s_waitcnt vmcnt(8)" ::: "memory");
        } else {
            asm volatile("s_waitcnt vmcnt(0)" ::: "memory");
        }
        __builtin_amdgcn_s_barrier();
        asm volatile("" ::: "memory");

        #pragma unroll
        for (int c8 = 0; c8 < 8; ++c8) {
            const _Float16* base = POOL + buf * EL_P1 + c8 * EL_CH;
            f32x4 s[4];
            #pragma unroll
            for (int nf = 0; nf < 4; ++nf) s[nf] = (f32x4){0.f, 0.f, 0.f, 0.f};
            qkt(base, aqA, s);
            float a = 0.f;
            #pragma unroll
            for (int nf = 0; nf < 4; ++nf)
                #pragma unroll
                for (int r = 0; r < 4; ++r) a += __expf(s[nf][r]);
            llA += a;

            #pragma unroll
            for (int nf = 0; nf < 4; ++nf) s[nf] = (f32x4){0.f, 0.f, 0.f, 0.f};
            qkt(base, aqB, s);
            float b = 0.f;
            #pragma unroll
            for (int nf = 0; nf < 4; ++nf)
                #pragma unroll
                for (int r = 0; r < 4; ++r) b += __expf(s[nf][r]);
            llB += b;
        }

        asm volatile("" ::: "memory");
        __builtin_amdgcn_s_barrier();
    }

    llA += __shfl_xor(llA, 16); llA += __shfl_xor(llA, 32);
    llB += __shfl_xor(llB, 16); llB += __shfl_xor(llB, 32);
    float rlA = 1.0f / llA, rlB = 1.0f / llB;

    // ========== pass 2: 128-key chunks; per-chunk, both tiles ==============
    f32x4 accA[4], accB[4];
    #pragma unroll
    for (int nf = 0; nf < 4; ++nf) {
        accA[nf] = (f32x4){0.f, 0.f, 0.f, 0.f};
        accB[nf] = (f32x4){0.f, 0.f, 0.f, 0.f};
    }

    float* attbA = att + ((size_t)bb * SEQ + (size_t)qt * 256 + w * 16) * SEQ;
    float* attbB = attbA + (size_t)128 * SEQ;

    auto stage_k2 = [&](int buf, int sc) {        // 2 gld16 (16 KB K chunk)
        const _Float16* g = khb + (size_t)sc * EL_SC + tid * 8;
        _Float16* d = POOL + buf * EL_SC;
        gld16(g,        d + w * 512);
        gld16(g + 4096, d + 4096 + w * 512);
    };
    auto stage_v2 = [&](int buf, int sc) {        // 2 gld16 (16 KB V chunk)
        const _Float16* g = vvb + (size_t)sc * EL_SC + tid * 8;
        _Float16* d = POOL + 16384 + buf * EL_SC;
        gld16(g,        d + w * 512);
        gld16(g + 4096, d + 4096 + w * 512);
    };

    // one tile's chunk: QK^T -> Ph -> att stores (512B runs) -> PV
    auto do_tile = [&](const _Float16* kc, const half8* v8, const half8* aq,
                       float rl, float* attb, int sc, f32x4* acc) {
        f32x4 sA[4], sB[4];
        #pragma unroll
        for (int nf = 0; nf < 4; ++nf) {
            sA[nf] = (f32x4){0.f, 0.f, 0.f, 0.f};
            sB[nf] = (f32x4){0.f, 0.f, 0.f, 0.f};
        }
        qkt(kc,         aq, sA);
        qkt(kc + EL_CH, aq, sB);

        #pragma unroll
        for (int nf = 0; nf < 4; ++nf) {
            half4 pa, pb;
            #pragma unroll
            for (int r = 0; r < 4; ++r) {
                pa[r] = (_Float16)(__expf(sA[nf][r]) * rl);
                pb[r] = (_Float16)(__expf(sB[nf][r]) * rl);
            }
            *(half4*)&Ph[li * PHS + nf * 16 + h4 * 4]      = pa;
            *(half4*)&Ph[li * PHS + 64 + nf * 16 + h4 * 4] = pb;
        }

        // att stores: 8 insts, each = 2 rows x (32 lanes x 16B = 512B run)
        #pragma unroll
        for (int j = 0; j < 8; ++j) {
            int row = j * 2 + (lane >> 5);
            int col = (lane & 31) * 4;
            half4 ph = *(const half4*)&Ph[row * PHS + col];
            f32x4 pv = { (float)ph[0], (float)ph[1], (float)ph[2], (float)ph[3] };
            __builtin_nontemporal_store(
                pv, (f32x4*)(attb + (size_t)row * SEQ + sc * 128 + col));
        }

        // PV over 128 keys: 16 MFMA
        #pragma unroll
        for (int kk = 0; kk < 4; ++kk) {
            half8 pa = *(const half8*)&Ph[li * PHS + kk * 32 + h4 * 8];
            #pragma unroll
            for (int nf = 0; nf < 4; ++nf)
                acc[nf] = __builtin_amdgcn_mfma_f32_16x16x32_f16(
                    pa, v8[(kk >> 1) * 512 + (nf * 2 + (kk & 1)) * 64 + lane],
                    acc[nf], 0, 0, 0);
        }
    };

    stage_k2(0, 0); stage_v2(0, 0);
    for (int sc = 0; sc < NP2; ++sc) {
        int buf = sc & 1;
        if (sc + 1 < NP2) {
            stage_k2(buf ^ 1, sc + 1);
            stage_v2(buf ^ 1, sc + 1);
            // queue: [4 loads cur][16 stores prev][4 loads next] -> vmcnt(20)
            if (sc == 0) asm volatile("s_waitcnt vmcnt(4)"  ::: "memory");
            else         asm volatile("s_waitcnt vmcnt(20)" ::: "memory");
        } else {
            // queue: [4 loads cur][16 stores prev]
            asm volatile("s_waitcnt vmcnt(16)" ::: "memory");
        }
        __builtin_amdgcn_s_barrier();
        asm volatile("" ::: "memory");

        const _Float16* kc = POOL + buf * EL_SC;
        const half8* v8 = (const half8*)(POOL + 16384 + buf * EL_SC);
        do_tile(kc, v8, aqA, rlA, attbA, sc, accA);
        do_tile(kc, v8, aqB, rlB, attbB, sc, accB);

        asm volatile("" ::: "memory");
        __builtin_amdgcn_s_barrier();
    }

    // ---- ctx: transpose via LDS -> contiguous NT stores, per tile ----
    __syncthreads();
    float* Phf = (float*)(POOL + 32768) + w * (16 * 68);
    float* ctxwA = ctx + ((size_t)bb * SEQ + (size_t)qt * 256 + w * 16) * DIM;
    #pragma unroll
    for (int t = 0; t < 2; ++t) {
        f32x4* acc = t ? accB : accA;
        float* ctxw = ctxwA + (size_t)t * 128 * DIM;
        #pragma unroll
        for (int nf = 0; nf < 4; ++nf)
            #pragma unroll
            for (int r = 0; r < 4; ++r)
                Phf[(4 * h4 + r) * 68 + nf * 16 + li] = acc[nf][r];
        asm volatile("s_waitcnt lgkmcnt(0)" ::: "memory");
        #pragma unroll
        for (int j = 0; j < 4; ++j) {
            int row = j * 4 + (lane >> 4);
            f32x4 cv = *(const f32x4*)&Phf[row * 68 + (lane & 15) * 4];
            __builtin_nontemporal_store(
                cv, (f32x4*)(ctxw + (size_t)row * DIM + (lane & 15) * 4));
        }
        asm volatile("s_waitcnt lgkmcnt(0)" ::: "memory");
    }
}

// ===================== fallback (round-2 kernel, proven) =====================
__global__ __launch_bounds__(256) void attn_fallback(
    const float* __restrict__ q, const float* __restrict__ k,
    const float* __restrict__ v, float* __restrict__ ctx,
    float* __restrict__ att)
{
    __shared__ short K_hi[KVB][72];
    __shared__ short K_lo[KVB][72];
    __shared__ short V_lds[DIM][72];
    __shared__ short P_lds[4][16][72];

    int id = blockIdx.x;
    int bb = (id & 7) + 8 * (id >> 9);
    int qt = (id >> 3) & 63;
    int tid = threadIdx.x;
    int w = tid >> 6, lane = tid & 63, li = lane & 15, h4 = lane >> 4;

    int qrow = qt * 64 + w * 16 + li;
    const float* qp = q + ((size_t)bb * SEQ + qrow) * DIM;
    short8 aq[2], aql[2];
    #pragma unroll
    for (int kk = 0; kk < 2; ++kk)
        #pragma unroll
        for (int e = 0; e < 8; ++e) {
            float x = qp[kk * 32 + h4 * 8 + e];
            short h = f2bf(x);
            aq[kk][e] = h; aql[kk][e] = f2bf(x - bf2f(h));
        }

    float m[4], l[4];
    #pragma unroll
    for (int r = 0; r < 4; ++r) { m[r] = -3.0e38f; l[r] = 0.0f; }
    const float* kbase = k + (size_t)bb * SEQ * DIM;
    const float* vbase = v + (size_t)bb * SEQ * DIM;

    for (int ch = 0; ch < NCH; ++ch) {
        __syncthreads();
        const float4* kc = (const float4*)(kbase + (size_t)ch * KVB * DIM);
        #pragma unroll
        for (int j = 0; j < 4; ++j) {
            int f4 = j * 256 + tid; int key = f4 >> 4, d4 = f4 & 15;
            float4 val = kc[f4];
            short4v h4v, l4v;
            h4v[0]=f2bf(val.x); l4v[0]=f2bf(val.x-bf2f(h4v[0]));
            h4v[1]=f2bf(val.y); l4v[1]=f2bf(val.y-bf2f(h4v[1]));
            h4v[2]=f2bf(val.z); l4v[2]=f2bf(val.z-bf2f(h4v[2]));
            h4v[3]=f2bf(val.w); l4v[3]=f2bf(val.w-bf2f(h4v[3]));
            *(short4v*)&K_hi[key][d4*4] = h4v;
            *(short4v*)&K_lo[key][d4*4] = l4v;
        }
        __syncthreads();
        f32x4 s[4];
        #pragma unroll
        for (int nf = 0; nf < 4; ++nf) s[nf] = (f32x4){0.f,0.f,0.f,0.f};
        #pragma unroll
        for (int kk = 0; kk < 2; ++kk)
            #pragma unroll
            for (int nf = 0; nf < 4; ++nf) {
                short8 kbv = *(const short8*)&K_hi[nf*16+li][kk*32+h4*8];
                short8 klv = *(const short8*)&K_lo[nf*16+li][kk*32+h4*8];
                s[nf] = __builtin_amdgcn_mfma_f32_16x16x32_bf16(aq[kk],  kbv, s[nf],0,0,0);
                s[nf] = __builtin_amdgcn_mfma_f32_16x16x32_bf16(aq[kk],  klv, s[nf],0,0,0);
                s[nf] = __builtin_amdgcn_mfma_f32_16x16x32_bf16(aql[kk], kbv, s[nf],0,0,0);
            }
        #pragma unroll
        for (int r = 0; r < 4; ++r) {
            float cmax = fmaxf(fmaxf(s[0][r],s[1][r]), fmaxf(s[2][r],s[3][r]));
            #pragma unroll
            for (int off = 1; off < 16; off <<= 1) cmax = fmaxf(cmax, __shfl_xor(cmax, off));
            float mnew = fmaxf(m[r], cmax);
            float cs = __expf(s[0][r]-mnew)+__expf(s[1][r]-mnew)+__expf(s[2][r]-mnew)+__expf(s[3][r]-mnew);
            #pragma unroll
            for (int off = 1; off < 16; off <<= 1) cs += __shfl_xor(cs, off);
            l[r] = l[r]*__expf(m[r]-mnew) + cs; m[r] = mnew;
        }
    }
    float rl[4];
    #pragma unroll
    for (int r = 0; r < 4; ++r) rl[r] = 1.0f / l[r];

    f32x4 acc[4];
    #pragma unroll
    for (int nf = 0; nf < 4; ++nf) acc[nf] = (f32x4){0.f,0.f,0.f,0.f};
    float* attb = att + ((size_t)bb * SEQ + (size_t)qt * 64 + w * 16) * SEQ;

    for (int ch = 0; ch < NCH; ++ch) {
        __syncthreads();
        const float4* kc = (const float4*)(kbase + (size_t)ch * KVB * DIM);
        #pragma unroll
        for (int j = 0; j < 4; ++j) {
            int f4 = j * 256 + tid; int key = f4 >> 4, d4 = f4 & 15;
            float4 val = kc[f4];
            short4v h4v, l4v;
            h4v[0]=f2bf(val.x); l4v[0]=f2bf(val.x-bf2f(h4v[0]));
            h4v[1]=f2bf(val.y); l4v[1]=f2bf(val.y-bf2f(h4v[1]));
            h4v[2]=f2bf(val.z); l4v[2]=f2bf(val.z-bf2f(h4v[2]));
            h4v[3]=f2bf(val.w); l4v[3]=f2bf(val.w-bf2f(h4v[3]));
            *(short4v*)&K_hi[key][d4*4] = h4v;
            *(short4v*)&K_lo[key][d4*4] = l4v;
        }
        {
            int key = tid & 63, dblk = (tid >> 6) * 16;
            const float* vc = vbase + ((size_t)ch * KVB + key) * DIM + dblk;
            #pragma unroll
            for (int j = 0; j < 4; ++j) {
                float4 val = *(const float4*)(vc + j * 4);
                V_lds[dblk+j*4+0][key]=f2bf(val.x); V_lds[dblk+j*4+1][key]=f2bf(val.y);
                V_lds[dblk+j*4+2][key]=f2bf(val.z); V_lds[dblk+j*4+3][key]=f2bf(val.w);
            }
        }
        __syncthreads();
        f32x4 s[4];
        #pragma unroll
        for (int nf = 0; nf < 4; ++nf) s[nf] = (f32x4){0.f,0.f,0.f,0.f};
        #pragma unroll
        for (int kk = 0; kk < 2; ++kk)
            #pragma unroll
            for (int nf = 0; nf < 4; ++nf) {
                short8 kbv = *(const short8*)&K_hi[nf*16+li][kk*32+h4*8];
                short8 klv = *(const short8*)&K_lo[nf*16+li][kk*32+h4*8];
                s[nf] = __builtin_amdgcn_mfma_f32_16x16x32_bf16(aq[kk],  kbv, s[nf],0,0,0);
                s[nf] = __builtin_amdgcn_mfma_f32_16x16x32_bf16(aq[kk],  klv, s[nf],0,0,0);
                s[nf] = __builtin_amdgcn_mfma_f32_16x16x32_bf16(aql[kk], kbv, s[nf],0,0,0);
            }
        #pragma unroll
        for (int nf = 0; nf < 4; ++nf)
            #pragma unroll
            for (int r = 0; r < 4; ++r) {
                float p = __expf(s[nf][r] - m[r]) * rl[r];
                __builtin_nontemporal_store(p, &attb[(size_t)(4*h4+r)*SEQ + ch*KVB + nf*16 + li]);
                P_lds[w][4*h4+r][nf*16+li] = f2bf(p);
            }
        #pragma unroll
        for (int kk = 0; kk < 2; ++kk) {
            short8 pa = *(const short8*)&P_lds[w][li][kk*32+h4*8];
            #pragma unroll
            for (int nf = 0; nf < 4; ++nf) {
                short8 vbv = *(const short8*)&V_lds[nf*16+li][kk*32+h4*8];
                acc[nf] = __builtin_amdgcn_mfma_f32_16x16x32_bf16(pa, vbv, acc[nf],0,0,0);
            }
        }
    }
    float* ctxb = ctx + ((size_t)bb * SEQ + (size_t)qt * 64 + w * 16) * DIM;
    #pragma unroll
    for (int nf = 0; nf < 4; ++nf)
        #pragma unroll
        for (int r = 0; r < 4; ++r)
            __builtin_nontemporal_store(acc[nf][r], &ctxb[(size_t)(4*h4+r)*DIM + nf*16 + li]);
}

extern "C" void kernel_launch(void* const* d_in, const int* in_sizes, int n_in,
                              void* d_out, int out_size, void* d_ws, size_t ws_size,
                              hipStream_t stream) {
    const float* q = (const float*)d_in[0];
    const float* k = (const float*)d_in[1];
    const float* v = (const float*)d_in[2];
    float* ctx = (float*)d_out;
    float* att = (float*)d_out + (size_t)BATCH * SEQ * DIM;

    const size_t t_el = (size_t)BATCH * EL_B;              // 4,194,304
    const size_t need = 2 * t_el * 2;                      // 16.8 MB

    if (ws_size >= need) {
        _Float16* kh = (_Float16*)d_ws;
        _Float16* vh = kh + t_el;
        preconvert<<<4096, 256, 0, stream>>>(k, v, kh, vh);
        attn_main<<<256, 512, 0, stream>>>(q, kh, vh, ctx, att);
    } else {
        attn_fallback<<<BATCH * (SEQ / 64), 256, 0, stream>>>(q, k, v, ctx, att);
    }
}